// Round 9
// baseline (165.714 us; speedup 1.0000x reference)
//
#include <hip/hip_runtime.h>
#include <hip/hip_bf16.h>
#include <math.h>

#define BATCH_N 8
#define SEQ_T   2048
#define DIM_D   1024
#define HS_N    128

using bf16x8_t = __attribute__((ext_vector_type(8))) __bf16;
using bf16x4_t = __attribute__((ext_vector_type(4))) __bf16;
using f32x4_t  = __attribute__((ext_vector_type(4))) float;

__device__ __forceinline__ f32x4_t mfma_16x16x32(bf16x8_t a, bf16x8_t b, f32x4_t c) {
  return __builtin_amdgcn_mfma_f32_16x16x32_bf16(a, b, c, 0, 0, 0);
}

// async global->LDS, 16B/lane; LDS dest = wave-uniform base + lane*16
__device__ __forceinline__ void async_cp16(const void* g, void* l) {
  __builtin_amdgcn_global_load_lds(
      (const __attribute__((address_space(1))) unsigned int*)g,
      (__attribute__((address_space(3))) unsigned int*)l, 16, 0, 0);
}

#define BAR()      __builtin_amdgcn_s_barrier()
#define FENCE()    asm volatile("" ::: "memory")
#define WAIT_VM(n) asm volatile("s_waitcnt vmcnt(" #n ")" ::: "memory")
#define WAIT_LGKM0 asm volatile("s_waitcnt lgkmcnt(0)" ::: "memory")
#define SCHEDBAR() __builtin_amdgcn_sched_barrier(0)

// ---------------------------------------------------------------------------
// Kernel 0: cast W -> bf16 in K-PANEL-MAJOR layout WbT[kt][n][kk]:
// panel kt (32 K-cols) is a contiguous 384x32 bf16 block (24576 B).
// Rows within panel: [K:0-127][Q:128-255][V:256-383], Q pre-scaled.
// This makes proj's per-wave B-fragment load a single fully-contiguous 1KB
// global_load_dwordx4 (addr = lr*64 + lq*16) -> no LDS staging needed for B.
// Also zeroes km.
// ---------------------------------------------------------------------------
__global__ __launch_bounds__(256) void castw_kernel(
    const float* __restrict__ Wk, const float* __restrict__ Wq,
    const float* __restrict__ Wv, __bf16* __restrict__ WbT,
    unsigned int* __restrict__ km) {
  if (blockIdx.x == 0 && threadIdx.x < 8) km[threadIdx.x] = 0u;
  int idx = blockIdx.x * 256 + threadIdx.x;
  int e   = idx * 4;
  int row = e >> 10;
  int col = e & 1023;
  const float* src;
  float sc = 1.0f;
  if (row < 128) {
    src = Wk + row * DIM_D + col;
  } else if (row < 256) {
    src = Wq + (row - 128) * DIM_D + col;
    sc  = 0.08838834764831845f;  // 1/sqrt(HS) folded into Wq
  } else {
    src = Wv + (row - 256) * DIM_D + col;
  }
  float4 v = *(const float4*)src;
  bf16x4_t o;
  o[0] = (__bf16)(v.x * sc); o[1] = (__bf16)(v.y * sc);
  o[2] = (__bf16)(v.z * sc); o[3] = (__bf16)(v.w * sc);
  const int pnl = col >> 5;       // K-panel 0..31
  const int c   = col & 31;       // within-panel col (multiple of 4)
  *(bf16x4_t*)(WbT + (size_t)pnl * 12288 + row * 32 + c) = o;
}

// ---------------------------------------------------------------------------
// Kernel 1: projections v17 — B OFF the staging path.
// R8 ledger: all variants plateau at ~44us = ~1MB/CU staged through
// global_load_lds at ~12B/cy/CU (request-rate bound: 64 lane-requests per
// 16B/lane call, ~1 req/cy/CU). Fix: B fragments load DIRECTLY global->VGPR
// as single coalesced 1KB global_load_dwordx4 (K-panel-major WbT layout),
// inline-asm with counted vmcnt (AITER pattern; R2's compiler-collapse fixed
// per rule #18: sched_barrier(0) after waits) and named double-buffer regs
// with manual unroll-by-2 (rule #20). Only A (8KB/iter fp32) stays on
// gload_lds (~500cy/iter, ~= MFMA time).
// BM=64, 512 thr (8 waves = 2 m-half x 4 n-grp), grid 256.
// Per iter/wave: stageA(kt+1) 1 call + 6 asm B-loads(kt+1); vmcnt(7); bar;
// 4 A ds_read_b128 + cvt + 12 MFMA (regs); lgkm0; bar.
// LDS = 2 x 8192 (A fp32 dbuf) = 16384 B. B values identical, accumulation
// order identical -> bit-identical Q/K/V. Fused knorm epilogue kept.
// ---------------------------------------------------------------------------
__global__ __launch_bounds__(512, 1) void proj_kernel(
    const float* __restrict__ x, const __bf16* __restrict__ WbT,
    __bf16* __restrict__ Qb, __bf16* __restrict__ Kb, __bf16* __restrict__ Vt,
    unsigned int* __restrict__ km) {
  __shared__ __align__(16) char psmem[16384];   // A: 2 x 8192 B

  const int tid  = threadIdx.x;
  const int lane = tid & 63;
  const int wave = tid >> 6;     // 0..7
  const int h    = wave >> 2;    // m-half (0..1)
  const int g    = wave & 3;     // n-group (0..3)
  const int lr = lane & 15;
  const int lq = lane >> 4;
  const int m0 = blockIdx.x * 64;

  f32x4_t acc[2][6];
  #pragma unroll
  for (int mt = 0; mt < 2; ++mt)
    #pragma unroll
    for (int nt = 0; nt < 6; ++nt) acc[mt][nt] = (f32x4_t){0.f, 0.f, 0.f, 0.f};

  // A chunk for step kt: rows m0..m0+63, cols kt*32..+31 (fp32, 8 x 16B/row).
  // Wave w stages rows w*8..w*8+7; LDS unit (r,j) holds logical j^(r&7).
  auto stageA = [&](int kt) {
    char* As = psmem + (kt & 1) * 8192;
    const int r = wave * 8 + (lane >> 3);
    const int c = (lane & 7) ^ ((lane >> 3) & 7);  // pre-swizzled 16B unit
    async_cp16(x + (size_t)(m0 + r) * DIM_D + kt * 32 + c * 4,
               As + wave * 1024);
  };

  // Per-fragment B lane pointers into WbT (panel-major): fragment nt of this
  // wave at panel kt = WbT + kt*12288 + (g*96+nt*16+lr)*32 + lq*8 — a wave's
  // 64 lanes cover one contiguous 1KB block.
  const __bf16* bp[6];
  #pragma unroll
  for (int nt = 0; nt < 6; ++nt)
    bp[nt] = WbT + (size_t)(g * 96 + nt * 16 + lr) * 32 + lq * 8;

  bf16x8_t bqA[6], bqB[6];

#define LOADB(kt, bq)                                                   \
  {                                                                     \
    _Pragma("unroll")                                                   \
    for (int nt = 0; nt < 6; ++nt) {                                    \
      const __bf16* p_ = bp[nt] + (size_t)(kt) * 12288;                 \
      asm volatile("global_load_dwordx4 %0, %1, off"                    \
                   : "=&v"(bq[nt]) : "v"(p_));                          \
    }                                                                   \
  }

  // Body for one K-step: consume LDS parity (kt&1) and the given B regs.
#define KSTEP(kt, bqCur, bqNxt)                                         \
  {                                                                     \
    if ((kt) + 1 < 32) {                                                \
      stageA((kt) + 1);                                                 \
      LOADB((kt) + 1, bqNxt);                                           \
      FENCE();                                                          \
      WAIT_VM(7);                                                       \
    } else {                                                            \
      WAIT_VM(0);                                                       \
    }                                                                   \
    BAR();                                                              \
    FENCE();                                                            \
    SCHEDBAR();                                                         \
    const float* As = (const float*)(psmem + ((kt) & 1) * 8192);        \
    bf16x8_t af[2];                                                     \
    _Pragma("unroll")                                                   \
    for (int mt = 0; mt < 2; ++mt) {                                    \
      const int ml = h * 32 + mt * 16 + lr;                             \
      const int u0 = (lq * 2) ^ (ml & 7);                               \
      const int u1 = (lq * 2 + 1) ^ (ml & 7);                           \
      f32x4_t lo = *(const f32x4_t*)(As + ml * 32 + u0 * 4);            \
      f32x4_t hi = *(const f32x4_t*)(As + ml * 32 + u1 * 4);            \
      bf16x8_t a;                                                       \
      a[0] = (__bf16)lo[0]; a[1] = (__bf16)lo[1];                       \
      a[2] = (__bf16)lo[2]; a[3] = (__bf16)lo[3];                       \
      a[4] = (__bf16)hi[0]; a[5] = (__bf16)hi[1];                       \
      a[6] = (__bf16)hi[2]; a[7] = (__bf16)hi[3];                       \
      af[mt] = a;                                                       \
    }                                                                   \
    _Pragma("unroll")                                                   \
    for (int mt = 0; mt < 2; ++mt)                                      \
      _Pragma("unroll")                                                 \
      for (int nt = 0; nt < 6; ++nt)                                    \
        acc[mt][nt] = mfma_16x16x32(af[mt], bqCur[nt], acc[mt][nt]);    \
    WAIT_LGKM0;                                                         \
    BAR();                                                              \
    FENCE();                                                            \
  }

  stageA(0);
  LOADB(0, bqA);
  FENCE();

  #pragma unroll 1
  for (int kt2 = 0; kt2 < 16; ++kt2) {
    const int kt = kt2 * 2;
    KSTEP(kt,     bqA, bqB);   // even: consume bqA, prefetch bqB
    KSTEP(kt + 1, bqB, bqA);   // odd:  consume bqB, prefetch bqA
  }
#undef KSTEP
#undef LOADB

  // ---- fused knorm: this block computes ALL 128 K-cols of rows m0..m0+63 ----
  __syncthreads();
  float* rowss = (float*)psmem;      // A region dead; reuse 64 floats
  if (tid < 64) rowss[tid] = 0.f;
  __syncthreads();
  if (g < 2) {                       // K cols live in g=0 (0..95), g=1 nt<2
    #pragma unroll
    for (int mt = 0; mt < 2; ++mt)
      #pragma unroll
      for (int r = 0; r < 4; ++r) {
        float s = 0.f;
        #pragma unroll
        for (int nt = 0; nt < 6; ++nt)
          if (g == 0 || nt < 2) s += acc[mt][nt][r] * acc[mt][nt][r];
        s += __shfl_xor(s, 1); s += __shfl_xor(s, 2);
        s += __shfl_xor(s, 4); s += __shfl_xor(s, 8);
        if (lr == 0) atomicAdd(&rowss[h * 32 + mt * 16 + lq * 4 + r], s);
      }
  }
  __syncthreads();
  if (tid < 64) {
    float v = rowss[tid];
    #pragma unroll
    for (int off = 1; off < 64; off <<= 1) v = fmaxf(v, __shfl_xor(v, off));
    if (tid == 0) atomicMax(km + (m0 >> 11), __float_as_uint(v));
  }

  #pragma unroll
  for (int mt = 0; mt < 2; ++mt) {
    const int t0 = m0 + h * 32 + mt * 16 + lq * 4;
    #pragma unroll
    for (int nt = 0; nt < 6; ++nt) {
      const int nn = g * 96 + nt * 16 + lr;
      if (nn < 256) {
        __bf16* dst = (nn < 128) ? (Kb + nn) : (Qb + (nn - 128));
        #pragma unroll
        for (int r = 0; r < 4; ++r)
          dst[(size_t)(t0 + r) * HS_N] = (__bf16)acc[mt][nt][r];
      } else {
        const int bb = t0 >> 11;
        const int tl = t0 & 2047;
        bf16x4_t o;
        #pragma unroll
        for (int r = 0; r < 4; ++r) o[r] = (__bf16)acc[mt][nt][r];
        *(bf16x4_t*)(Vt + (size_t)bb * (HS_N * SEQ_T) + (size_t)(nn - 256) * SEQ_T + tl) = o;
      }
    }
  }
}

// ---------------------------------------------------------------------------
// Kernel 2: flash attention v7 (R3-verified, unchanged). Grid 512: bid =
// b + 8*rest, rest = (15-jg)*4 + p4 (heavy-first). Each block owns a quarter
// of q-tile jg's key range. LDS 81920 -> 2 blocks/CU. Counted vmcnt(8) +
// dual raw barriers per chunk. No device-scope fences (R4 lesson).
// ---------------------------------------------------------------------------
__global__ __launch_bounds__(256, 2) void attn_kernel(
    const __bf16* __restrict__ Qb, const __bf16* __restrict__ Kb,
    const __bf16* __restrict__ Vt, const unsigned int* __restrict__ km,
    __bf16* __restrict__ Opart, float* __restrict__ lpart) {
  __shared__ __align__(16) char smem[81920];
  __bf16* KsBase = (__bf16*)smem;                    // 2 x 16 KB
  __bf16* VsBase = (__bf16*)(smem + 32768);          // 2 x 16 KB
  float*  Ofl    = (float*)smem;                     // 128x132 fp32, post-loop

  const int lane = threadIdx.x & 63;
  const int wave = threadIdx.x >> 6;       // 0..3
  const int lr = lane & 15;
  const int lq = lane >> 4;
  const int bid  = blockIdx.x;
  const int b    = bid & 7;                // batch -> XCD pinned
  const int rest = bid >> 3;               // 0..63
  const int jg   = 15 - (rest >> 2);       // heavy-first
  const int p4   = rest & 3;               // key quarter
  const int Q0   = jg * 128;
  const int qa   = Q0 + wave * 32;         // this wave's 32 rows (2 tiles)
  const int ch   = 2 * (jg + 1);           // total 64-key chunks for this jg
  const int c0   = (p4 * ch) >> 2;         // this part's chunk range [c0,c1)
  const int c1   = ((p4 + 1) * ch) >> 2;

  const __bf16* Qbb = Qb + (size_t)b * (SEQ_T * HS_N);
  const __bf16* Kbb = Kb + (size_t)b * (SEQ_T * HS_N);
  const __bf16* Vbb = Vt + (size_t)b * (HS_N * SEQ_T);
  __bf16* pbA = (__bf16*)(smem + 65536 + wave * 4096);         // 16x64 bf16
  __bf16* pbB = (__bf16*)(smem + 65536 + wave * 4096 + 2048);  // 16x64 bf16

  bf16x8_t qf[2][4];
  #pragma unroll
  for (int t = 0; t < 2; ++t)
    #pragma unroll
    for (int ks = 0; ks < 4; ++ks)
      qf[t][ks] = *(const bf16x8_t*)(Qbb + (size_t)(qa + t * 16 + lr) * HS_N
                                     + ks * 32 + lq * 8);

  const float km2 = __uint_as_float(km[b]);
  float mrow[2][4];
  #pragma unroll
  for (int t = 0; t < 2; ++t) {
    float qn2 = 0.f;
    #pragma unroll
    for (int ks = 0; ks < 4; ++ks)
      #pragma unroll
      for (int j = 0; j < 8; ++j) { float f = (float)qf[t][ks][j]; qn2 += f * f; }
    qn2 += __shfl_xor(qn2, 16);
    qn2 += __shfl_xor(qn2, 32);
    #pragma unroll
    for (int r2 = 0; r2 < 4; ++r2)
      mrow[t][r2] = sqrtf(__shfl(qn2, lq * 4 + r2) * km2);
  }

  f32x4_t Oa[2][8];
  #pragma unroll
  for (int t = 0; t < 2; ++t)
    #pragma unroll
    for (int o = 0; o < 8; ++o) Oa[t][o] = (f32x4_t){0.f, 0.f, 0.f, 0.f};
  float lsum[2][4] = {{0.f,0.f,0.f,0.f},{0.f,0.f,0.f,0.f}};

  auto stage = [&](int bufi, int c) {
    const int kk = c * 64;
    __bf16* Ks = KsBase + bufi * 8192;
    for (int idx = wave; idx < 32; idx += 4) {   // 8 x 16B loads per wave
      if (idx < 16) {          // K: 4 rows x 256B per call
        const int row = idx * 4 + (lane >> 4);
        const int u   = (lane & 15) ^ (row & 15);
        async_cp16(Kbb + (size_t)(kk + row) * HS_N + u * 8, Ks + idx * 512);
      } else {                 // V: 8 rows x 128B per call (rows = HS dims)
        const int i2  = idx - 16;
        const int row = i2 * 8 + (lane >> 3);
        const int u   = (lane & 7) ^ (row & 7);
        async_cp16(Vbb + (size_t)row * SEQ_T + kk + u * 8, VsBase + bufi * 8192 + i2 * 512);
      }
    }
  };

  if (c0 < c1) stage(0, c0);
  __syncthreads();   // prologue: full drain once

  for (int c = c0; c < c1; ++c) {
    const int cur = (c - c0) & 1;
    if (c + 1 < c1) {
      stage(cur ^ 1, c + 1);   // 8 loads/wave stay in flight across BAR
      WAIT_VM(8);              // only chunk c's batch must be complete
    } else {
      WAIT_VM(0);
    }
    BAR();                     // all waves: buf[cur] fully written
    FENCE();

    const int kk = c * 64;
    const __bf16* Ks = KsBase + cur * 8192;
    const __bf16* Vs = VsBase + cur * 8192;

    f32x4_t s0[4], s1[4];
    #pragma unroll
    for (int nt = 0; nt < 4; ++nt) {
      s0[nt] = (f32x4_t){0.f, 0.f, 0.f, 0.f};
      s1[nt] = (f32x4_t){0.f, 0.f, 0.f, 0.f};
    }
    #pragma unroll
    for (int ks = 0; ks < 4; ++ks)
      #pragma unroll
      for (int nt = 0; nt < 4; ++nt) {
        bf16x8_t kf = *(const bf16x8_t*)(
            &Ks[(nt * 16 + lr) * 128 + (((ks * 4 + lq) ^ lr) * 8)]);
        s0[nt] = mfma_16x16x32(qf[0][ks], kf, s0[nt]);
        s1[nt] = mfma_16x16x32(qf[1][ks], kf, s1[nt]);
      }
    const int q0a = qa, q0b = qa + 16;
    if (kk + 63 > q0a) {
      #pragma unroll
      for (int nt = 0; nt < 4; ++nt) {
        const int col = kk + nt * 16 + lr;
        #pragma unroll
        for (int r2 = 0; r2 < 4; ++r2)
          if (col > q0a + lq * 4 + r2) s0[nt][r2] = -INFINITY;
      }
    }
    if (kk + 63 > q0b) {
      #pragma unroll
      for (int nt = 0; nt < 4; ++nt) {
        const int col = kk + nt * 16 + lr;
        #pragma unroll
        for (int r2 = 0; r2 < 4; ++r2)
          if (col > q0b + lq * 4 + r2) s1[nt][r2] = -INFINITY;
      }
    }

    #pragma unroll
    for (int r2 = 0; r2 < 4; ++r2) {
      float a0 = __expf(s0[0][r2] - mrow[0][r2]);
      float a1 = __expf(s0[1][r2] - mrow[0][r2]);
      float a2 = __expf(s0[2][r2] - mrow[0][r2]);
      float a3 = __expf(s0[3][r2] - mrow[0][r2]);
      s0[0][r2] = a0; s0[1][r2] = a1; s0[2][r2] = a2; s0[3][r2] = a3;
      lsum[0][r2] += (a0 + a1) + (a2 + a3);
      float b0 = __expf(s1[0][r2] - mrow[1][r2]);
      float b1 = __expf(s1[1][r2] - mrow[1][r2]);
      float b2 = __expf(s1[2][r2] - mrow[1][r2]);
      float b3 = __expf(s1[3][r2] - mrow[1][r2]);
      s1[0][r2] = b0; s1[1][r2] = b1; s1[2][r2] = b2; s1[3][r2] = b3;
      lsum[1][r2] += (b0 + b1) + (b2 + b3);
    }

    #pragma unroll
    for (int nt = 0; nt < 4; ++nt)
      #pragma unroll
      for (int r2 = 0; r2 < 4; ++r2) {
        const int prow = lq * 4 + r2;
        const int pcol = (nt * 16 + lr) ^ ((prow & 7) << 3);
        pbA[prow * 64 + pcol] = (__bf16)s0[nt][r2];
        pbB[prow * 64 + pcol] = (__bf16)s1[nt][r2];
      }

    #pragma unroll
    for (int k2 = 0; k2 < 2; ++k2) {
      const int au = ((k2 * 4 + lq) ^ (lr & 7)) << 3;
      bf16x8_t afrA = *(const bf16x8_t*)(pbA + lr * 64 + au);
      bf16x8_t afrB = *(const bf16x8_t*)(pbB + lr * 64 + au);
      #pragma unroll
      for (int o = 0; o < 8; ++o) {
        bf16x8_t vfr = *(const bf16x8_t*)(
            &Vs[(o * 16 + lr) * 64 + (((k2 * 4 + lq) ^ (lr & 7)) * 8)]);
        Oa[0][o] = mfma_16x16x32(afrA, vfr, Oa[0][o]);
        Oa[1][o] = mfma_16x16x32(afrB, vfr, Oa[1][o]);
      }
    }
    WAIT_LGKM0;                // my LDS reads (K/V/P) complete
    BAR();                     // release buf[cur] for overwrite next iter
    FENCE();
  }

  #pragma unroll
  for (int t = 0; t < 2; ++t)
    #pragma unroll
    for (int r2 = 0; r2 < 4; ++r2) {
      float v = lsum[t][r2];
      v += __shfl_xor(v, 1);
      v += __shfl_xor(v, 2);
      v += __shfl_xor(v, 4);
      v += __shfl_xor(v, 8);
      if (lr == 0)
        lpart[bid * 128 + wave * 32 + t * 16 + lq * 4 + r2] = v;
    }

  #pragma unroll
  for (int t = 0; t < 2; ++t)
    #pragma unroll
    for (int o = 0; o < 8; ++o)
      #pragma unroll
      for (int r2 = 0; r2 < 4; ++r2)
        Ofl[(wave * 32 + t * 16 + lq * 4 + r2) * 132 + o * 16 + lr] = Oa[t][o][r2];
  __syncthreads();

  {
    const int row = threadIdx.x >> 1;
    const int cb  = (threadIdx.x & 1) * 64;
    __bf16* dst = Opart + ((size_t)bid * 128 + row) * 128 + cb;
    #pragma unroll
    for (int g2 = 0; g2 < 16; ++g2) {
      float4 f = *(const float4*)(&Ofl[row * 132 + cb + g2 * 4]);
      bf16x4_t o;
      o[0] = (__bf16)f.x; o[1] = (__bf16)f.y; o[2] = (__bf16)f.z; o[3] = (__bf16)f.w;
      *(bf16x4_t*)(dst + g2 * 4) = o;
    }
  }
}

// ---------------------------------------------------------------------------
// Kernel 3: merge the 4 key-quarters: out = (sum O_p) / (sum l_p)
// ---------------------------------------------------------------------------
__global__ __launch_bounds__(256) void merge_kernel(
    const __bf16* __restrict__ Opart, const float* __restrict__ lpart,
    float* __restrict__ out) {
  const int idx = blockIdx.x * 256 + threadIdx.x;   // 524288 threads
  const int row = idx >> 5;                         // global row 0..16383
  const int c4  = (idx & 31) * 4;
  const int b   = row >> 11;
  const int tl  = row & 2047;
  const int jg  = tl >> 7;
  const int lrow = tl & 127;
  const int rbase = (15 - jg) * 4;
  float a0 = 0.f, a1 = 0.f, a2 = 0.f, a3 = 0.f, l = 0.f;
  #pragma unroll
  for (int p = 0; p < 4; ++p) {
    const int s = b + 8 * (rbase + p);
    bf16x4_t a = *(const bf16x4_t*)(Opart + ((size_t)s * 128 + lrow) * 128 + c4);
    a0 += (float)a[0]; a1 += (float)a[1]; a2 += (float)a[2]; a3 += (float)a[3];
    l += lpart[s * 128 + lrow];
  }
  const float inv = 1.0f / l;
  float4 o;
  o.x = a0 * inv; o.y = a1 * inv; o.z = a2 * inv; o.w = a3 * inv;
  *(float4*)(out + (size_t)row * HS_N + c4) = o;
}

// ---------------------------------------------------------------------------
extern "C" void kernel_launch(void* const* d_in, const int* in_sizes, int n_in,
                              void* d_out, int out_size, void* d_ws, size_t ws_size,
                              hipStream_t stream) {
  const float* x  = (const float*)d_in[0];
  const float* Wk = (const float*)d_in[1];
  const float* Wq = (const float*)d_in[2];
  const float* Wv = (const float*)d_in[3];
  float* out = (float*)d_out;

  char* ws = (char*)d_ws;
  __bf16* WbT = (__bf16*)ws;                         //   786432 B
  __bf16* Qb = (__bf16*)(ws + 786432);               //  4194304 B
  __bf16* Kb = (__bf16*)(ws + 786432 + 4194304);     //  4194304 B
  __bf16* Vt = (__bf16*)(ws + 786432 + 8388608);     //  4194304 B
  unsigned int* km = (unsigned int*)(ws + 13369344); //       32 B
  __bf16* Opart = (__bf16*)(ws + 13369600);          // 16777216 B (512x128x128)
  float*  lpart = (float*)(ws + 30146816);           //   262144 B

  castw_kernel<<<384, 256, 0, stream>>>(Wk, Wq, Wv, WbT, km);
  proj_kernel<<<256, 512, 0, stream>>>(x, WbT, Qb, Kb, Vt, km);
  attn_kernel<<<512, 256, 0, stream>>>(Qb, Kb, Vt, km, Opart, lpart);
  merge_kernel<<<2048, 256, 0, stream>>>(Opart, lpart, out);
}

// Round 10
// 152.458 us; speedup vs baseline: 1.0869x; 1.0869x over previous
//
#include <hip/hip_runtime.h>
#include <hip/hip_bf16.h>
#include <math.h>

#define BATCH_N 8
#define SEQ_T   2048
#define DIM_D   1024
#define HS_N    128

using bf16x8_t = __attribute__((ext_vector_type(8))) __bf16;
using bf16x4_t = __attribute__((ext_vector_type(4))) __bf16;
using f32x4_t  = __attribute__((ext_vector_type(4))) float;

__device__ __forceinline__ f32x4_t mfma_16x16x32(bf16x8_t a, bf16x8_t b, f32x4_t c) {
  return __builtin_amdgcn_mfma_f32_16x16x32_bf16(a, b, c, 0, 0, 0);
}

// async global->LDS, 16B/lane; LDS dest = wave-uniform base + lane*16
__device__ __forceinline__ void async_cp16(const void* g, void* l) {
  __builtin_amdgcn_global_load_lds(
      (const __attribute__((address_space(1))) unsigned int*)g,
      (__attribute__((address_space(3))) unsigned int*)l, 16, 0, 0);
}

#define BAR()      __builtin_amdgcn_s_barrier()
#define FENCE()    asm volatile("" ::: "memory")
#define WAIT_VM(n) asm volatile("s_waitcnt vmcnt(" #n ")" ::: "memory")
#define WAIT_LGKM0 asm volatile("s_waitcnt lgkmcnt(0)" ::: "memory")

// ---------------------------------------------------------------------------
// Kernel 0: cast W -> bf16, rows [K:0-127][Q:128-255][V:256-383], Q pre-scaled.
// Also zeroes km. (Row-major Wb — R5 layout.)
// ---------------------------------------------------------------------------
__global__ __launch_bounds__(256) void castw_kernel(
    const float* __restrict__ Wk, const float* __restrict__ Wq,
    const float* __restrict__ Wv, __bf16* __restrict__ Wb,
    unsigned int* __restrict__ km) {
  if (blockIdx.x == 0 && threadIdx.x < 8) km[threadIdx.x] = 0u;
  int idx = blockIdx.x * 256 + threadIdx.x;
  int e   = idx * 4;
  int row = e >> 10;
  int col = e & 1023;
  const float* src;
  float sc = 1.0f;
  if (row < 128) {
    src = Wk + row * DIM_D + col;
  } else if (row < 256) {
    src = Wq + (row - 128) * DIM_D + col;
    sc  = 0.08838834764831845f;  // 1/sqrt(HS) folded into Wq
  } else {
    src = Wv + (row - 256) * DIM_D + col;
  }
  float4 v = *(const float4*)src;
  bf16x4_t o;
  o[0] = (__bf16)(v.x * sc); o[1] = (__bf16)(v.y * sc);
  o[2] = (__bf16)(v.z * sc); o[3] = (__bf16)(v.w * sc);
  *(bf16x4_t*)(Wb + e) = o;
}

// ---------------------------------------------------------------------------
// Kernel 1: projections v18 — v13 (best-known: BM=64, tbuf, fused knorm)
// + PER-BLOCK K-STAGGER. R9 ledger: every structural variant (barriers,
// B-volume, buffer depth, cast-phase, lockstep, staging path) plateaus at
// 44-52us -> the invariant is that ALL blocks read the IDENTICAL W panel in
// the IDENTICAL kt order simultaneously; per-XCD L2 has no multicast, so
// same-line requests from 32 CUs serialize at the owning L2 bank every iter.
// Fix: block bid consumes panels in order (kt2 + (bid&15)) & 15 within each
// phase (A is phase-resident -> any within-phase order valid; B staging maps
// logical->physical panel). 16 offsets -> collisions /16; same-XCD blocks
// get offsets differing by 8. Accumulation order over kt changes (fp32 sum
// reorder, << bf16 quantization noise).
// LDS = 65536 (A) + 3x24576 (B tbuf) = 139264 -> 1 block/CU.
// ---------------------------------------------------------------------------
__global__ __launch_bounds__(512, 1) void proj_kernel(
    const float* __restrict__ x, const __bf16* __restrict__ Wb,
    __bf16* __restrict__ Qb, __bf16* __restrict__ Kb, __bf16* __restrict__ Vt,
    unsigned int* __restrict__ km) {
  __shared__ __align__(16) char psmem[139264];
  __bf16* A = (__bf16*)psmem;                       // 64 x 512 bf16 = 64 KB

  const int tid  = threadIdx.x;
  const int lane = tid & 63;
  const int wave = tid >> 6;     // 0..7
  const int h    = wave >> 2;    // m-half (0..1)
  const int g    = wave & 3;     // n-group (0..3)
  const int lr = lane & 15;
  const int lq = lane >> 4;
  const int m0 = blockIdx.x * 64;
  const int boff = blockIdx.x & 15;   // per-block panel stagger

  f32x4_t acc[2][6];
  #pragma unroll
  for (int mt = 0; mt < 2; ++mt)
    #pragma unroll
    for (int nt = 0; nt < 6; ++nt) acc[mt][nt] = (f32x4_t){0.f, 0.f, 0.f, 0.f};

  // Stage the PHYSICAL panel for logical step ktL into buf[ktL % 3].
  auto stageB = [&](int ktL) {
    const int phys = (ktL & 16) + ((ktL + boff) & 15);
    __bf16* Bs = (__bf16*)(psmem + 65536 + (ktL % 3) * 24576);
    for (int c = wave; c < 24; c += 8) {     // 3 x 16B loads per wave
      const int row = c * 16 + (lane >> 2);
      const int u   = (lane & 3) ^ ((row >> 1) & 3);
      async_cp16(Wb + (size_t)row * DIM_D + phys * 32 + u * 8, Bs + c * 512);
    }
  };

  stageB(0);
  stageB(1);

  for (int p = 0; p < 2; ++p) {
    __syncthreads();   // phase boundary: full drain OK (2x/kernel)

    // ---- cast this phase's x slab (64 rows x 512 cols) fp32->bf16 into LDS ----
    {
      const int r  = tid >> 3;        // 0..63
      const int t  = tid & 7;
      const float* xs = x + (size_t)(m0 + r) * DIM_D + p * 512;
      __bf16* as = A + r * 512;
      const int sw = r & 7;
      #pragma unroll
      for (int i = 0; i < 8; ++i) {
        const int u = t + 8 * i;      // 16B units (8 bf16) within the phase
        float4 f0 = *(const float4*)(xs + u * 8);
        float4 f1 = *(const float4*)(xs + u * 8 + 4);
        bf16x8_t a;
        a[0] = (__bf16)f0.x; a[1] = (__bf16)f0.y;
        a[2] = (__bf16)f0.z; a[3] = (__bf16)f0.w;
        a[4] = (__bf16)f1.x; a[5] = (__bf16)f1.y;
        a[6] = (__bf16)f1.z; a[7] = (__bf16)f1.w;
        *(bf16x8_t*)(as + ((u ^ sw) * 8)) = a;
      }
    }
    __syncthreads();   // A ready

    for (int kt2 = 0; kt2 < 16; ++kt2) {
      const int kt   = p * 16 + kt2;            // logical step
      const int ktp2 = (kt2 + boff) & 15;       // physical sub-panel in phase
      if (kt + 2 < 32) stageB(kt + 2);          // depth-2 prefetch in flight
      if (kt < 30)       { WAIT_VM(6); }        // batches kt+1, kt+2 in flight
      else if (kt == 30) { WAIT_VM(3); }
      else               { WAIT_VM(0); }
      BAR();                                    // buf[kt%3] fully written
      FENCE();
      const __bf16* Bs = (const __bf16*)(psmem + 65536 + (kt % 3) * 24576);

      bf16x8_t af[2];
      #pragma unroll
      for (int mt = 0; mt < 2; ++mt) {
        const int ml = h * 32 + mt * 16 + lr;
        const int u  = ktp2 * 4 + lq;           // A col matches physical panel
        af[mt] = *(const bf16x8_t*)(&A[ml * 512 + ((u ^ (ml & 7)) * 8)]);
      }
      bf16x8_t bfv[6];
      #pragma unroll
      for (int nt = 0; nt < 6; ++nt) {
        const int nl = g * 96 + nt * 16 + lr;
        bfv[nt] = *(const bf16x8_t*)(&Bs[nl * 32 + ((lq ^ ((nl >> 1) & 3)) * 8)]);
      }
      #pragma unroll
      for (int mt = 0; mt < 2; ++mt)
        #pragma unroll
        for (int nt = 0; nt < 6; ++nt)
          acc[mt][nt] = mfma_16x16x32(af[mt], bfv[nt], acc[mt][nt]);
      WAIT_LGKM0;                    // my LDS reads landed in regs
      BAR();                         // release buf[(kt+2)%3] target
      FENCE();
    }
  }

  // ---- fused knorm: this block computes ALL 128 K-cols of rows m0..m0+63 ----
  __syncthreads();
  float* rowss = (float*)psmem;      // A region dead; reuse 64 floats
  if (tid < 64) rowss[tid] = 0.f;
  __syncthreads();
  if (g < 2) {                       // K cols live in g=0 (0..95), g=1 nt<2
    #pragma unroll
    for (int mt = 0; mt < 2; ++mt)
      #pragma unroll
      for (int r = 0; r < 4; ++r) {
        float s = 0.f;
        #pragma unroll
        for (int nt = 0; nt < 6; ++nt)
          if (g == 0 || nt < 2) s += acc[mt][nt][r] * acc[mt][nt][r];
        s += __shfl_xor(s, 1); s += __shfl_xor(s, 2);
        s += __shfl_xor(s, 4); s += __shfl_xor(s, 8);
        if (lr == 0) atomicAdd(&rowss[h * 32 + mt * 16 + lq * 4 + r], s);
      }
  }
  __syncthreads();
  if (tid < 64) {
    float v = rowss[tid];
    #pragma unroll
    for (int off = 1; off < 64; off <<= 1) v = fmaxf(v, __shfl_xor(v, off));
    if (tid == 0) atomicMax(km + (m0 >> 11), __float_as_uint(v));
  }

  #pragma unroll
  for (int mt = 0; mt < 2; ++mt) {
    const int t0 = m0 + h * 32 + mt * 16 + lq * 4;
    #pragma unroll
    for (int nt = 0; nt < 6; ++nt) {
      const int nn = g * 96 + nt * 16 + lr;
      if (nn < 256) {
        __bf16* dst = (nn < 128) ? (Kb + nn) : (Qb + (nn - 128));
        #pragma unroll
        for (int r = 0; r < 4; ++r)
          dst[(size_t)(t0 + r) * HS_N] = (__bf16)acc[mt][nt][r];
      } else {
        const int bb = t0 >> 11;
        const int tl = t0 & 2047;
        bf16x4_t o;
        #pragma unroll
        for (int r = 0; r < 4; ++r) o[r] = (__bf16)acc[mt][nt][r];
        *(bf16x4_t*)(Vt + (size_t)bb * (HS_N * SEQ_T) + (size_t)(nn - 256) * SEQ_T + tl) = o;
      }
    }
  }
}

// ---------------------------------------------------------------------------
// Kernel 2: flash attention v7 (R3-verified, unchanged). Grid 512: bid =
// b + 8*rest, rest = (15-jg)*4 + p4 (heavy-first). Each block owns a quarter
// of q-tile jg's key range. LDS 81920 -> 2 blocks/CU. Counted vmcnt(8) +
// dual raw barriers per chunk. No device-scope fences (R4 lesson).
// ---------------------------------------------------------------------------
__global__ __launch_bounds__(256, 2) void attn_kernel(
    const __bf16* __restrict__ Qb, const __bf16* __restrict__ Kb,
    const __bf16* __restrict__ Vt, const unsigned int* __restrict__ km,
    __bf16* __restrict__ Opart, float* __restrict__ lpart) {
  __shared__ __align__(16) char smem[81920];
  __bf16* KsBase = (__bf16*)smem;                    // 2 x 16 KB
  __bf16* VsBase = (__bf16*)(smem + 32768);          // 2 x 16 KB
  float*  Ofl    = (float*)smem;                     // 128x132 fp32, post-loop

  const int lane = threadIdx.x & 63;
  const int wave = threadIdx.x >> 6;       // 0..3
  const int lr = lane & 15;
  const int lq = lane >> 4;
  const int bid  = blockIdx.x;
  const int b    = bid & 7;                // batch -> XCD pinned
  const int rest = bid >> 3;               // 0..63
  const int jg   = 15 - (rest >> 2);       // heavy-first
  const int p4   = rest & 3;               // key quarter
  const int Q0   = jg * 128;
  const int qa   = Q0 + wave * 32;         // this wave's 32 rows (2 tiles)
  const int ch   = 2 * (jg + 1);           // total 64-key chunks for this jg
  const int c0   = (p4 * ch) >> 2;         // this part's chunk range [c0,c1)
  const int c1   = ((p4 + 1) * ch) >> 2;

  const __bf16* Qbb = Qb + (size_t)b * (SEQ_T * HS_N);
  const __bf16* Kbb = Kb + (size_t)b * (SEQ_T * HS_N);
  const __bf16* Vbb = Vt + (size_t)b * (HS_N * SEQ_T);
  __bf16* pbA = (__bf16*)(smem + 65536 + wave * 4096);         // 16x64 bf16
  __bf16* pbB = (__bf16*)(smem + 65536 + wave * 4096 + 2048);  // 16x64 bf16

  bf16x8_t qf[2][4];
  #pragma unroll
  for (int t = 0; t < 2; ++t)
    #pragma unroll
    for (int ks = 0; ks < 4; ++ks)
      qf[t][ks] = *(const bf16x8_t*)(Qbb + (size_t)(qa + t * 16 + lr) * HS_N
                                     + ks * 32 + lq * 8);

  const float km2 = __uint_as_float(km[b]);
  float mrow[2][4];
  #pragma unroll
  for (int t = 0; t < 2; ++t) {
    float qn2 = 0.f;
    #pragma unroll
    for (int ks = 0; ks < 4; ++ks)
      #pragma unroll
      for (int j = 0; j < 8; ++j) { float f = (float)qf[t][ks][j]; qn2 += f * f; }
    qn2 += __shfl_xor(qn2, 16);
    qn2 += __shfl_xor(qn2, 32);
    #pragma unroll
    for (int r2 = 0; r2 < 4; ++r2)
      mrow[t][r2] = sqrtf(__shfl(qn2, lq * 4 + r2) * km2);
  }

  f32x4_t Oa[2][8];
  #pragma unroll
  for (int t = 0; t < 2; ++t)
    #pragma unroll
    for (int o = 0; o < 8; ++o) Oa[t][o] = (f32x4_t){0.f, 0.f, 0.f, 0.f};
  float lsum[2][4] = {{0.f,0.f,0.f,0.f},{0.f,0.f,0.f,0.f}};

  auto stage = [&](int bufi, int c) {
    const int kk = c * 64;
    __bf16* Ks = KsBase + bufi * 8192;
    for (int idx = wave; idx < 32; idx += 4) {   // 8 x 16B loads per wave
      if (idx < 16) {          // K: 4 rows x 256B per call
        const int row = idx * 4 + (lane >> 4);
        const int u   = (lane & 15) ^ (row & 15);
        async_cp16(Kbb + (size_t)(kk + row) * HS_N + u * 8, Ks + idx * 512);
      } else {                 // V: 8 rows x 128B per call (rows = HS dims)
        const int i2  = idx - 16;
        const int row = i2 * 8 + (lane >> 3);
        const int u   = (lane & 7) ^ (row & 7);
        async_cp16(Vbb + (size_t)row * SEQ_T + kk + u * 8, VsBase + bufi * 8192 + i2 * 512);
      }
    }
  };

  if (c0 < c1) stage(0, c0);
  __syncthreads();   // prologue: full drain once

  for (int c = c0; c < c1; ++c) {
    const int cur = (c - c0) & 1;
    if (c + 1 < c1) {
      stage(cur ^ 1, c + 1);   // 8 loads/wave stay in flight across BAR
      WAIT_VM(8);              // only chunk c's batch must be complete
    } else {
      WAIT_VM(0);
    }
    BAR();                     // all waves: buf[cur] fully written
    FENCE();

    const int kk = c * 64;
    const __bf16* Ks = KsBase + cur * 8192;
    const __bf16* Vs = VsBase + cur * 8192;

    f32x4_t s0[4], s1[4];
    #pragma unroll
    for (int nt = 0; nt < 4; ++nt) {
      s0[nt] = (f32x4_t){0.f, 0.f, 0.f, 0.f};
      s1[nt] = (f32x4_t){0.f, 0.f, 0.f, 0.f};
    }
    #pragma unroll
    for (int ks = 0; ks < 4; ++ks)
      #pragma unroll
      for (int nt = 0; nt < 4; ++nt) {
        bf16x8_t kf = *(const bf16x8_t*)(
            &Ks[(nt * 16 + lr) * 128 + (((ks * 4 + lq) ^ lr) * 8)]);
        s0[nt] = mfma_16x16x32(qf[0][ks], kf, s0[nt]);
        s1[nt] = mfma_16x16x32(qf[1][ks], kf, s1[nt]);
      }
    const int q0a = qa, q0b = qa + 16;
    if (kk + 63 > q0a) {
      #pragma unroll
      for (int nt = 0; nt < 4; ++nt) {
        const int col = kk + nt * 16 + lr;
        #pragma unroll
        for (int r2 = 0; r2 < 4; ++r2)
          if (col > q0a + lq * 4 + r2) s0[nt][r2] = -INFINITY;
      }
    }
    if (kk + 63 > q0b) {
      #pragma unroll
      for (int nt = 0; nt < 4; ++nt) {
        const int col = kk + nt * 16 + lr;
        #pragma unroll
        for (int r2 = 0; r2 < 4; ++r2)
          if (col > q0b + lq * 4 + r2) s1[nt][r2] = -INFINITY;
      }
    }

    #pragma unroll
    for (int r2 = 0; r2 < 4; ++r2) {
      float a0 = __expf(s0[0][r2] - mrow[0][r2]);
      float a1 = __expf(s0[1][r2] - mrow[0][r2]);
      float a2 = __expf(s0[2][r2] - mrow[0][r2]);
      float a3 = __expf(s0[3][r2] - mrow[0][r2]);
      s0[0][r2] = a0; s0[1][r2] = a1; s0[2][r2] = a2; s0[3][r2] = a3;
      lsum[0][r2] += (a0 + a1) + (a2 + a3);
      float b0 = __expf(s1[0][r2] - mrow[1][r2]);
      float b1 = __expf(s1[1][r2] - mrow[1][r2]);
      float b2 = __expf(s1[2][r2] - mrow[1][r2]);
      float b3 = __expf(s1[3][r2] - mrow[1][r2]);
      s1[0][r2] = b0; s1[1][r2] = b1; s1[2][r2] = b2; s1[3][r2] = b3;
      lsum[1][r2] += (b0 + b1) + (b2 + b3);
    }

    #pragma unroll
    for (int nt = 0; nt < 4; ++nt)
      #pragma unroll
      for (int r2 = 0; r2 < 4; ++r2) {
        const int prow = lq * 4 + r2;
        const int pcol = (nt * 16 + lr) ^ ((prow & 7) << 3);
        pbA[prow * 64 + pcol] = (__bf16)s0[nt][r2];
        pbB[prow * 64 + pcol] = (__bf16)s1[nt][r2];
      }

    #pragma unroll
    for (int k2 = 0; k2 < 2; ++k2) {
      const int au = ((k2 * 4 + lq) ^ (lr & 7)) << 3;
      bf16x8_t afrA = *(const bf16x8_t*)(pbA + lr * 64 + au);
      bf16x8_t afrB = *(const bf16x8_t*)(pbB + lr * 64 + au);
      #pragma unroll
      for (int o = 0; o < 8; ++o) {
        bf16x8_t vfr = *(const bf16x8_t*)(
            &Vs[(o * 16 + lr) * 64 + (((k2 * 4 + lq) ^ (lr & 7)) * 8)]);
        Oa[0][o] = mfma_16x16x32(afrA, vfr, Oa[0][o]);
        Oa[1][o] = mfma_16x16x32(afrB, vfr, Oa[1][o]);
      }
    }
    WAIT_LGKM0;                // my LDS reads (K/V/P) complete
    BAR();                     // release buf[cur] for overwrite next iter
    FENCE();
  }

  #pragma unroll
  for (int t = 0; t < 2; ++t)
    #pragma unroll
    for (int r2 = 0; r2 < 4; ++r2) {
      float v = lsum[t][r2];
      v += __shfl_xor(v, 1);
      v += __shfl_xor(v, 2);
      v += __shfl_xor(v, 4);
      v += __shfl_xor(v, 8);
      if (lr == 0)
        lpart[bid * 128 + wave * 32 + t * 16 + lq * 4 + r2] = v;
    }

  #pragma unroll
  for (int t = 0; t < 2; ++t)
    #pragma unroll
    for (int o = 0; o < 8; ++o)
      #pragma unroll
      for (int r2 = 0; r2 < 4; ++r2)
        Ofl[(wave * 32 + t * 16 + lq * 4 + r2) * 132 + o * 16 + lr] = Oa[t][o][r2];
  __syncthreads();

  {
    const int row = threadIdx.x >> 1;
    const int cb  = (threadIdx.x & 1) * 64;
    __bf16* dst = Opart + ((size_t)bid * 128 + row) * 128 + cb;
    #pragma unroll
    for (int g2 = 0; g2 < 16; ++g2) {
      float4 f = *(const float4*)(&Ofl[row * 132 + cb + g2 * 4]);
      bf16x4_t o;
      o[0] = (__bf16)f.x; o[1] = (__bf16)f.y; o[2] = (__bf16)f.z; o[3] = (__bf16)f.w;
      *(bf16x4_t*)(dst + g2 * 4) = o;
    }
  }
}

// ---------------------------------------------------------------------------
// Kernel 3: merge the 4 key-quarters: out = (sum O_p) / (sum l_p)
// ---------------------------------------------------------------------------
__global__ __launch_bounds__(256) void merge_kernel(
    const __bf16* __restrict__ Opart, const float* __restrict__ lpart,
    float* __restrict__ out) {
  const int idx = blockIdx.x * 256 + threadIdx.x;   // 524288 threads
  const int row = idx >> 5;                         // global row 0..16383
  const int c4  = (idx & 31) * 4;
  const int b   = row >> 11;
  const int tl  = row & 2047;
  const int jg  = tl >> 7;
  const int lrow = tl & 127;
  const int rbase = (15 - jg) * 4;
  float a0 = 0.f, a1 = 0.f, a2 = 0.f, a3 = 0.f, l = 0.f;
  #pragma unroll
  for (int p = 0; p < 4; ++p) {
    const int s = b + 8 * (rbase + p);
    bf16x4_t a = *(const bf16x4_t*)(Opart + ((size_t)s * 128 + lrow) * 128 + c4);
    a0 += (float)a[0]; a1 += (float)a[1]; a2 += (float)a[2]; a3 += (float)a[3];
    l += lpart[s * 128 + lrow];
  }
  const float inv = 1.0f / l;
  float4 o;
  o.x = a0 * inv; o.y = a1 * inv; o.z = a2 * inv; o.w = a3 * inv;
  *(float4*)(out + (size_t)row * HS_N + c4) = o;
}

// ---------------------------------------------------------------------------
extern "C" void kernel_launch(void* const* d_in, const int* in_sizes, int n_in,
                              void* d_out, int out_size, void* d_ws, size_t ws_size,
                              hipStream_t stream) {
  const float* x  = (const float*)d_in[0];
  const float* Wk = (const float*)d_in[1];
  const float* Wq = (const float*)d_in[2];
  const float* Wv = (const float*)d_in[3];
  float* out = (float*)d_out;

  char* ws = (char*)d_ws;
  __bf16* Wb = (__bf16*)ws;                          //   786432 B
  __bf16* Qb = (__bf16*)(ws + 786432);               //  4194304 B
  __bf16* Kb = (__bf16*)(ws + 786432 + 4194304);     //  4194304 B
  __bf16* Vt = (__bf16*)(ws + 786432 + 8388608);     //  4194304 B
  unsigned int* km = (unsigned int*)(ws + 13369344); //       32 B
  __bf16* Opart = (__bf16*)(ws + 13369600);          // 16777216 B (512x128x128)
  float*  lpart = (float*)(ws + 30146816);           //   262144 B

  castw_kernel<<<384, 256, 0, stream>>>(Wk, Wq, Wv, Wb, km);
  proj_kernel<<<256, 512, 0, stream>>>(x, Wb, Qb, Kb, Vt, km);
  attn_kernel<<<512, 256, 0, stream>>>(Qb, Kb, Vt, km, Opart, lpart);
  merge_kernel<<<2048, 256, 0, stream>>>(Opart, lpart, out);
}

// Round 11
// 148.260 us; speedup vs baseline: 1.1177x; 1.0283x over previous
//
#include <hip/hip_runtime.h>
#include <hip/hip_bf16.h>
#include <math.h>

#define BATCH_N 8
#define SEQ_T   2048
#define DIM_D   1024
#define HS_N    128

using bf16x8_t = __attribute__((ext_vector_type(8))) __bf16;
using bf16x4_t = __attribute__((ext_vector_type(4))) __bf16;
using f32x4_t  = __attribute__((ext_vector_type(4))) float;

__device__ __forceinline__ f32x4_t mfma_16x16x32(bf16x8_t a, bf16x8_t b, f32x4_t c) {
  return __builtin_amdgcn_mfma_f32_16x16x32_bf16(a, b, c, 0, 0, 0);
}

// async global->LDS, 16B/lane; LDS dest = wave-uniform base + lane*16
__device__ __forceinline__ void async_cp16(const void* g, void* l) {
  __builtin_amdgcn_global_load_lds(
      (const __attribute__((address_space(1))) unsigned int*)g,
      (__attribute__((address_space(3))) unsigned int*)l, 16, 0, 0);
}

#define BAR()      __builtin_amdgcn_s_barrier()
#define FENCE()    asm volatile("" ::: "memory")
#define WAIT_VM(n) asm volatile("s_waitcnt vmcnt(" #n ")" ::: "memory")
#define WAIT_LGKM0 asm volatile("s_waitcnt lgkmcnt(0)" ::: "memory")

// ---------------------------------------------------------------------------
// Kernel 0: cast W -> bf16, rows [K:0-127][Q:128-255][V:256-383], Q pre-scaled.
// Also zeroes km.
// ---------------------------------------------------------------------------
__global__ __launch_bounds__(256) void castw_kernel(
    const float* __restrict__ Wk, const float* __restrict__ Wq,
    const float* __restrict__ Wv, __bf16* __restrict__ Wb,
    unsigned int* __restrict__ km) {
  if (blockIdx.x == 0 && threadIdx.x < 8) km[threadIdx.x] = 0u;
  int idx = blockIdx.x * 256 + threadIdx.x;
  int e   = idx * 4;
  int row = e >> 10;
  int col = e & 1023;
  const float* src;
  float sc = 1.0f;
  if (row < 128) {
    src = Wk + row * DIM_D + col;
  } else if (row < 256) {
    src = Wq + (row - 128) * DIM_D + col;
    sc  = 0.08838834764831845f;  // 1/sqrt(HS) folded into Wq
  } else {
    src = Wv + (row - 256) * DIM_D + col;
  }
  float4 v = *(const float4*)src;
  bf16x4_t o;
  o[0] = (__bf16)(v.x * sc); o[1] = (__bf16)(v.y * sc);
  o[2] = (__bf16)(v.z * sc); o[3] = (__bf16)(v.w * sc);
  *(bf16x4_t*)(Wb + e) = o;
}

// ---------------------------------------------------------------------------
// Kernel 1: projections v19 — ONE barrier per K-step, ZERO lgkm drains.
// R10 ledger closed every data-path theory; the untouched invariant was
// 2 barriers + full lgkmcnt(0) drain per K-step (m233: that structure is
// ~72% sync overhead). Fix: quad-buffered B -> the trailing lgkm0+BAR is
// provably removable: stage at iter kt targets buf[(kt+2)%4], last READ at
// iter kt-2; the stager has passed BAR(kt-1), which transitively implies all
// waves' iter-(kt-2) MFMAs (which consume those ds_reads under compiler
// lgkmcnt) completed. 64 barriers + 32 drains -> 32 barriers + 0 drains.
// BM=64, 512 thr (8 waves = 2 m-half x 4 n-grp), grid 256. A in 4 phases
// (64x256 slab = 32 KB); B quad 4x24576 = 96 KB; LDS = 131072 -> 1 block/CU.
// Counted vmcnt(6/3/0), depth-2 prefetch. Accumulation order = v13 ->
// bit-identical Q/K/V. Fused knorm epilogue kept.
// ---------------------------------------------------------------------------
__global__ __launch_bounds__(512, 1) void proj_kernel(
    const float* __restrict__ x, const __bf16* __restrict__ Wb,
    __bf16* __restrict__ Qb, __bf16* __restrict__ Kb, __bf16* __restrict__ Vt,
    unsigned int* __restrict__ km) {
  __shared__ __align__(16) char psmem[131072];
  __bf16* A = (__bf16*)psmem;                       // 64 x 256 bf16 = 32 KB

  const int tid  = threadIdx.x;
  const int lane = tid & 63;
  const int wave = tid >> 6;     // 0..7
  const int h    = wave >> 2;    // m-half (0..1)
  const int g    = wave & 3;     // n-group (0..3)
  const int lr = lane & 15;
  const int lq = lane >> 4;
  const int m0 = blockIdx.x * 64;

  f32x4_t acc[2][6];
  #pragma unroll
  for (int mt = 0; mt < 2; ++mt)
    #pragma unroll
    for (int nt = 0; nt < 6; ++nt) acc[mt][nt] = (f32x4_t){0.f, 0.f, 0.f, 0.f};

  auto stageB = [&](int kt) {
    __bf16* Bs = (__bf16*)(psmem + 32768 + (kt & 3) * 24576);
    for (int c = wave; c < 24; c += 8) {     // 3 x 16B loads per wave
      const int row = c * 16 + (lane >> 2);
      const int u   = (lane & 3) ^ ((row >> 1) & 3);
      async_cp16(Wb + (size_t)row * DIM_D + kt * 32 + u * 8, Bs + c * 512);
    }
  };

  stageB(0);
  stageB(1);

  for (int p = 0; p < 4; ++p) {
    __syncthreads();   // protect A before overwrite (4x/kernel; full drain OK)

    // ---- cast this phase's x slab (64 rows x 256 cols) fp32->bf16 into LDS ----
    {
      const int r  = tid >> 3;        // 0..63
      const int t  = tid & 7;
      const float* xs = x + (size_t)(m0 + r) * DIM_D + p * 256;
      __bf16* as = A + r * 256;
      const int sw = r & 7;
      #pragma unroll
      for (int i = 0; i < 4; ++i) {
        const int u = t + 8 * i;      // 8-bf16 units within the phase (0..31)
        float4 f0 = *(const float4*)(xs + u * 8);
        float4 f1 = *(const float4*)(xs + u * 8 + 4);
        bf16x8_t a;
        a[0] = (__bf16)f0.x; a[1] = (__bf16)f0.y;
        a[2] = (__bf16)f0.z; a[3] = (__bf16)f0.w;
        a[4] = (__bf16)f1.x; a[5] = (__bf16)f1.y;
        a[6] = (__bf16)f1.z; a[7] = (__bf16)f1.w;
        *(bf16x8_t*)(as + ((u ^ sw) * 8)) = a;
      }
    }
    __syncthreads();   // A ready for this phase

    for (int kt2 = 0; kt2 < 8; ++kt2) {
      const int kt = p * 8 + kt2;
      if (kt + 2 < 32) {
        stageB(kt + 2);              // depth-2 prefetch stays in flight
        WAIT_VM(6);                  // wait only batch kt (kt+1,kt+2 younger)
      } else if (kt == 30) {
        WAIT_VM(3);                  // only batch 31 younger
      } else {
        WAIT_VM(0);                  // kt == 31
      }
      BAR();                         // all waves: buf[kt&3] fully written
      FENCE();
      const __bf16* Bs = (const __bf16*)(psmem + 32768 + (kt & 3) * 24576);

      bf16x8_t af[2];
      #pragma unroll
      for (int mt = 0; mt < 2; ++mt) {
        const int ml = h * 32 + mt * 16 + lr;
        const int u  = kt2 * 4 + lq;           // unit 0..31 within phase
        af[mt] = *(const bf16x8_t*)(&A[ml * 256 + ((u ^ (ml & 7)) * 8)]);
      }
      bf16x8_t bfv[6];
      #pragma unroll
      for (int nt = 0; nt < 6; ++nt) {
        const int nl = g * 96 + nt * 16 + lr;
        bfv[nt] = *(const bf16x8_t*)(&Bs[nl * 32 + ((lq ^ ((nl >> 1) & 3)) * 8)]);
      }
      #pragma unroll
      for (int mt = 0; mt < 2; ++mt)
        #pragma unroll
        for (int nt = 0; nt < 6; ++nt)
          acc[mt][nt] = mfma_16x16x32(af[mt], bfv[nt], acc[mt][nt]);
      // NO trailing lgkm drain / barrier: quad-buffer + BAR-transitivity
      // makes the next overwrite of buf[kt&3] (stage kt+4, issued at iter
      // kt+2 after BAR(kt+1)) safe.
    }
  }

  // ---- fused knorm: this block computes ALL 128 K-cols of rows m0..m0+63 ----
  __syncthreads();
  float* rowss = (float*)psmem;      // A region dead; reuse 64 floats
  if (tid < 64) rowss[tid] = 0.f;
  __syncthreads();
  if (g < 2) {                       // K cols live in g=0 (0..95), g=1 nt<2
    #pragma unroll
    for (int mt = 0; mt < 2; ++mt)
      #pragma unroll
      for (int r = 0; r < 4; ++r) {
        float s = 0.f;
        #pragma unroll
        for (int nt = 0; nt < 6; ++nt)
          if (g == 0 || nt < 2) s += acc[mt][nt][r] * acc[mt][nt][r];
        s += __shfl_xor(s, 1); s += __shfl_xor(s, 2);
        s += __shfl_xor(s, 4); s += __shfl_xor(s, 8);
        if (lr == 0) atomicAdd(&rowss[h * 32 + mt * 16 + lq * 4 + r], s);
      }
  }
  __syncthreads();
  if (tid < 64) {
    float v = rowss[tid];
    #pragma unroll
    for (int off = 1; off < 64; off <<= 1) v = fmaxf(v, __shfl_xor(v, off));
    if (tid == 0) atomicMax(km + (m0 >> 11), __float_as_uint(v));
  }

  #pragma unroll
  for (int mt = 0; mt < 2; ++mt) {
    const int t0 = m0 + h * 32 + mt * 16 + lq * 4;
    #pragma unroll
    for (int nt = 0; nt < 6; ++nt) {
      const int nn = g * 96 + nt * 16 + lr;
      if (nn < 256) {
        __bf16* dst = (nn < 128) ? (Kb + nn) : (Qb + (nn - 128));
        #pragma unroll
        for (int r = 0; r < 4; ++r)
          dst[(size_t)(t0 + r) * HS_N] = (__bf16)acc[mt][nt][r];
      } else {
        const int bb = t0 >> 11;
        const int tl = t0 & 2047;
        bf16x4_t o;
        #pragma unroll
        for (int r = 0; r < 4; ++r) o[r] = (__bf16)acc[mt][nt][r];
        *(bf16x4_t*)(Vt + (size_t)bb * (HS_N * SEQ_T) + (size_t)(nn - 256) * SEQ_T + tl) = o;
      }
    }
  }
}

// ---------------------------------------------------------------------------
// Kernel 2: flash attention v7 (R3-verified, unchanged). Grid 512: bid =
// b + 8*rest, rest = (15-jg)*4 + p4 (heavy-first). Each block owns a quarter
// of q-tile jg's key range. LDS 81920 -> 2 blocks/CU. Counted vmcnt(8) +
// dual raw barriers per chunk. No device-scope fences (R4 lesson).
// ---------------------------------------------------------------------------
__global__ __launch_bounds__(256, 2) void attn_kernel(
    const __bf16* __restrict__ Qb, const __bf16* __restrict__ Kb,
    const __bf16* __restrict__ Vt, const unsigned int* __restrict__ km,
    __bf16* __restrict__ Opart, float* __restrict__ lpart) {
  __shared__ __align__(16) char smem[81920];
  __bf16* KsBase = (__bf16*)smem;                    // 2 x 16 KB
  __bf16* VsBase = (__bf16*)(smem + 32768);          // 2 x 16 KB
  float*  Ofl    = (float*)smem;                     // 128x132 fp32, post-loop

  const int lane = threadIdx.x & 63;
  const int wave = threadIdx.x >> 6;       // 0..3
  const int lr = lane & 15;
  const int lq = lane >> 4;
  const int bid  = blockIdx.x;
  const int b    = bid & 7;                // batch -> XCD pinned
  const int rest = bid >> 3;               // 0..63
  const int jg   = 15 - (rest >> 2);       // heavy-first
  const int p4   = rest & 3;               // key quarter
  const int Q0   = jg * 128;
  const int qa   = Q0 + wave * 32;         // this wave's 32 rows (2 tiles)
  const int ch   = 2 * (jg + 1);           // total 64-key chunks for this jg
  const int c0   = (p4 * ch) >> 2;         // this part's chunk range [c0,c1)
  const int c1   = ((p4 + 1) * ch) >> 2;

  const __bf16* Qbb = Qb + (size_t)b * (SEQ_T * HS_N);
  const __bf16* Kbb = Kb + (size_t)b * (SEQ_T * HS_N);
  const __bf16* Vbb = Vt + (size_t)b * (HS_N * SEQ_T);
  __bf16* pbA = (__bf16*)(smem + 65536 + wave * 4096);         // 16x64 bf16
  __bf16* pbB = (__bf16*)(smem + 65536 + wave * 4096 + 2048);  // 16x64 bf16

  bf16x8_t qf[2][4];
  #pragma unroll
  for (int t = 0; t < 2; ++t)
    #pragma unroll
    for (int ks = 0; ks < 4; ++ks)
      qf[t][ks] = *(const bf16x8_t*)(Qbb + (size_t)(qa + t * 16 + lr) * HS_N
                                     + ks * 32 + lq * 8);

  const float km2 = __uint_as_float(km[b]);
  float mrow[2][4];
  #pragma unroll
  for (int t = 0; t < 2; ++t) {
    float qn2 = 0.f;
    #pragma unroll
    for (int ks = 0; ks < 4; ++ks)
      #pragma unroll
      for (int j = 0; j < 8; ++j) { float f = (float)qf[t][ks][j]; qn2 += f * f; }
    qn2 += __shfl_xor(qn2, 16);
    qn2 += __shfl_xor(qn2, 32);
    #pragma unroll
    for (int r2 = 0; r2 < 4; ++r2)
      mrow[t][r2] = sqrtf(__shfl(qn2, lq * 4 + r2) * km2);
  }

  f32x4_t Oa[2][8];
  #pragma unroll
  for (int t = 0; t < 2; ++t)
    #pragma unroll
    for (int o = 0; o < 8; ++o) Oa[t][o] = (f32x4_t){0.f, 0.f, 0.f, 0.f};
  float lsum[2][4] = {{0.f,0.f,0.f,0.f},{0.f,0.f,0.f,0.f}};

  auto stage = [&](int bufi, int c) {
    const int kk = c * 64;
    __bf16* Ks = KsBase + bufi * 8192;
    for (int idx = wave; idx < 32; idx += 4) {   // 8 x 16B loads per wave
      if (idx < 16) {          // K: 4 rows x 256B per call
        const int row = idx * 4 + (lane >> 4);
        const int u   = (lane & 15) ^ (row & 15);
        async_cp16(Kbb + (size_t)(kk + row) * HS_N + u * 8, Ks + idx * 512);
      } else {                 // V: 8 rows x 128B per call (rows = HS dims)
        const int i2  = idx - 16;
        const int row = i2 * 8 + (lane >> 3);
        const int u   = (lane & 7) ^ (row & 7);
        async_cp16(Vbb + (size_t)row * SEQ_T + kk + u * 8, VsBase + bufi * 8192 + i2 * 512);
      }
    }
  };

  if (c0 < c1) stage(0, c0);
  __syncthreads();   // prologue: full drain once

  for (int c = c0; c < c1; ++c) {
    const int cur = (c - c0) & 1;
    if (c + 1 < c1) {
      stage(cur ^ 1, c + 1);   // 8 loads/wave stay in flight across BAR
      WAIT_VM(8);              // only chunk c's batch must be complete
    } else {
      WAIT_VM(0);
    }
    BAR();                     // all waves: buf[cur] fully written
    FENCE();

    const int kk = c * 64;
    const __bf16* Ks = KsBase + cur * 8192;
    const __bf16* Vs = VsBase + cur * 8192;

    f32x4_t s0[4], s1[4];
    #pragma unroll
    for (int nt = 0; nt < 4; ++nt) {
      s0[nt] = (f32x4_t){0.f, 0.f, 0.f, 0.f};
      s1[nt] = (f32x4_t){0.f, 0.f, 0.f, 0.f};
    }
    #pragma unroll
    for (int ks = 0; ks < 4; ++ks)
      #pragma unroll
      for (int nt = 0; nt < 4; ++nt) {
        bf16x8_t kf = *(const bf16x8_t*)(
            &Ks[(nt * 16 + lr) * 128 + (((ks * 4 + lq) ^ lr) * 8)]);
        s0[nt] = mfma_16x16x32(qf[0][ks], kf, s0[nt]);
        s1[nt] = mfma_16x16x32(qf[1][ks], kf, s1[nt]);
      }
    const int q0a = qa, q0b = qa + 16;
    if (kk + 63 > q0a) {
      #pragma unroll
      for (int nt = 0; nt < 4; ++nt) {
        const int col = kk + nt * 16 + lr;
        #pragma unroll
        for (int r2 = 0; r2 < 4; ++r2)
          if (col > q0a + lq * 4 + r2) s0[nt][r2] = -INFINITY;
      }
    }
    if (kk + 63 > q0b) {
      #pragma unroll
      for (int nt = 0; nt < 4; ++nt) {
        const int col = kk + nt * 16 + lr;
        #pragma unroll
        for (int r2 = 0; r2 < 4; ++r2)
          if (col > q0b + lq * 4 + r2) s1[nt][r2] = -INFINITY;
      }
    }

    #pragma unroll
    for (int r2 = 0; r2 < 4; ++r2) {
      float a0 = __expf(s0[0][r2] - mrow[0][r2]);
      float a1 = __expf(s0[1][r2] - mrow[0][r2]);
      float a2 = __expf(s0[2][r2] - mrow[0][r2]);
      float a3 = __expf(s0[3][r2] - mrow[0][r2]);
      s0[0][r2] = a0; s0[1][r2] = a1; s0[2][r2] = a2; s0[3][r2] = a3;
      lsum[0][r2] += (a0 + a1) + (a2 + a3);
      float b0 = __expf(s1[0][r2] - mrow[1][r2]);
      float b1 = __expf(s1[1][r2] - mrow[1][r2]);
      float b2 = __expf(s1[2][r2] - mrow[1][r2]);
      float b3 = __expf(s1[3][r2] - mrow[1][r2]);
      s1[0][r2] = b0; s1[1][r2] = b1; s1[2][r2] = b2; s1[3][r2] = b3;
      lsum[1][r2] += (b0 + b1) + (b2 + b3);
    }

    #pragma unroll
    for (int nt = 0; nt < 4; ++nt)
      #pragma unroll
      for (int r2 = 0; r2 < 4; ++r2) {
        const int prow = lq * 4 + r2;
        const int pcol = (nt * 16 + lr) ^ ((prow & 7) << 3);
        pbA[prow * 64 + pcol] = (__bf16)s0[nt][r2];
        pbB[prow * 64 + pcol] = (__bf16)s1[nt][r2];
      }

    #pragma unroll
    for (int k2 = 0; k2 < 2; ++k2) {
      const int au = ((k2 * 4 + lq) ^ (lr & 7)) << 3;
      bf16x8_t afrA = *(const bf16x8_t*)(pbA + lr * 64 + au);
      bf16x8_t afrB = *(const bf16x8_t*)(pbB + lr * 64 + au);
      #pragma unroll
      for (int o = 0; o < 8; ++o) {
        bf16x8_t vfr = *(const bf16x8_t*)(
            &Vs[(o * 16 + lr) * 64 + (((k2 * 4 + lq) ^ (lr & 7)) * 8)]);
        Oa[0][o] = mfma_16x16x32(afrA, vfr, Oa[0][o]);
        Oa[1][o] = mfma_16x16x32(afrB, vfr, Oa[1][o]);
      }
    }
    WAIT_LGKM0;                // my LDS reads (K/V/P) complete
    BAR();                     // release buf[cur] for overwrite next iter
    FENCE();
  }

  #pragma unroll
  for (int t = 0; t < 2; ++t)
    #pragma unroll
    for (int r2 = 0; r2 < 4; ++r2) {
      float v = lsum[t][r2];
      v += __shfl_xor(v, 1);
      v += __shfl_xor(v, 2);
      v += __shfl_xor(v, 4);
      v += __shfl_xor(v, 8);
      if (lr == 0)
        lpart[bid * 128 + wave * 32 + t * 16 + lq * 4 + r2] = v;
    }

  #pragma unroll
  for (int t = 0; t < 2; ++t)
    #pragma unroll
    for (int o = 0; o < 8; ++o)
      #pragma unroll
      for (int r2 = 0; r2 < 4; ++r2)
        Ofl[(wave * 32 + t * 16 + lq * 4 + r2) * 132 + o * 16 + lr] = Oa[t][o][r2];
  __syncthreads();

  {
    const int row = threadIdx.x >> 1;
    const int cb  = (threadIdx.x & 1) * 64;
    __bf16* dst = Opart + ((size_t)bid * 128 + row) * 128 + cb;
    #pragma unroll
    for (int g2 = 0; g2 < 16; ++g2) {
      float4 f = *(const float4*)(&Ofl[row * 132 + cb + g2 * 4]);
      bf16x4_t o;
      o[0] = (__bf16)f.x; o[1] = (__bf16)f.y; o[2] = (__bf16)f.z; o[3] = (__bf16)f.w;
      *(bf16x4_t*)(dst + g2 * 4) = o;
    }
  }
}

// ---------------------------------------------------------------------------
// Kernel 3: merge the 4 key-quarters: out = (sum O_p) / (sum l_p)
// ---------------------------------------------------------------------------
__global__ __launch_bounds__(256) void merge_kernel(
    const __bf16* __restrict__ Opart, const float* __restrict__ lpart,
    float* __restrict__ out) {
  const int idx = blockIdx.x * 256 + threadIdx.x;   // 524288 threads
  const int row = idx >> 5;                         // global row 0..16383
  const int c4  = (idx & 31) * 4;
  const int b   = row >> 11;
  const int tl  = row & 2047;
  const int jg  = tl >> 7;
  const int lrow = tl & 127;
  const int rbase = (15 - jg) * 4;
  float a0 = 0.f, a1 = 0.f, a2 = 0.f, a3 = 0.f, l = 0.f;
  #pragma unroll
  for (int p = 0; p < 4; ++p) {
    const int s = b + 8 * (rbase + p);
    bf16x4_t a = *(const bf16x4_t*)(Opart + ((size_t)s * 128 + lrow) * 128 + c4);
    a0 += (float)a[0]; a1 += (float)a[1]; a2 += (float)a[2]; a3 += (float)a[3];
    l += lpart[s * 128 + lrow];
  }
  const float inv = 1.0f / l;
  float4 o;
  o.x = a0 * inv; o.y = a1 * inv; o.z = a2 * inv; o.w = a3 * inv;
  *(float4*)(out + (size_t)row * HS_N + c4) = o;
}

// ---------------------------------------------------------------------------
extern "C" void kernel_launch(void* const* d_in, const int* in_sizes, int n_in,
                              void* d_out, int out_size, void* d_ws, size_t ws_size,
                              hipStream_t stream) {
  const float* x  = (const float*)d_in[0];
  const float* Wk = (const float*)d_in[1];
  const float* Wq = (const float*)d_in[2];
  const float* Wv = (const float*)d_in[3];
  float* out = (float*)d_out;

  char* ws = (char*)d_ws;
  __bf16* Wb = (__bf16*)ws;                          //   786432 B
  __bf16* Qb = (__bf16*)(ws + 786432);               //  4194304 B
  __bf16* Kb = (__bf16*)(ws + 786432 + 4194304);     //  4194304 B
  __bf16* Vt = (__bf16*)(ws + 786432 + 8388608);     //  4194304 B
  unsigned int* km = (unsigned int*)(ws + 13369344); //       32 B
  __bf16* Opart = (__bf16*)(ws + 13369600);          // 16777216 B (512x128x128)
  float*  lpart = (float*)(ws + 30146816);           //   262144 B

  castw_kernel<<<384, 256, 0, stream>>>(Wk, Wq, Wv, Wb, km);
  proj_kernel<<<256, 512, 0, stream>>>(x, Wb, Qb, Kb, Vt, km);
  attn_kernel<<<512, 256, 0, stream>>>(Qb, Kb, Vt, km, Opart, lpart);
  merge_kernel<<<2048, 256, 0, stream>>>(Opart, lpart, out);
}

// Round 12
// 145.604 us; speedup vs baseline: 1.1381x; 1.0182x over previous
//
#include <hip/hip_runtime.h>
#include <hip/hip_bf16.h>
#include <math.h>

#define BATCH_N 8
#define SEQ_T   2048
#define DIM_D   1024
#define HS_N    128

using bf16x8_t = __attribute__((ext_vector_type(8))) __bf16;
using bf16x4_t = __attribute__((ext_vector_type(4))) __bf16;
using f32x4_t  = __attribute__((ext_vector_type(4))) float;

__device__ __forceinline__ f32x4_t mfma_16x16x32(bf16x8_t a, bf16x8_t b, f32x4_t c) {
  return __builtin_amdgcn_mfma_f32_16x16x32_bf16(a, b, c, 0, 0, 0);
}

// async global->LDS, 16B/lane; LDS dest = wave-uniform base + lane*16
__device__ __forceinline__ void async_cp16(const void* g, void* l) {
  __builtin_amdgcn_global_load_lds(
      (const __attribute__((address_space(1))) unsigned int*)g,
      (__attribute__((address_space(3))) unsigned int*)l, 16, 0, 0);
}

#define BAR()      __builtin_amdgcn_s_barrier()
#define FENCE()    asm volatile("" ::: "memory")
#define WAIT_VM(n) asm volatile("s_waitcnt vmcnt(" #n ")" ::: "memory")
#define WAIT_LGKM0 asm volatile("s_waitcnt lgkmcnt(0)" ::: "memory")
#define SCHEDBAR() __builtin_amdgcn_sched_barrier(0)

// attn work partition: P parts per (b,jg), P = ceil(2(jg+1)/5) -> max 5
// chunks/part, 61 slots per batch, heavy-first slot order.
__device__ const unsigned char SJG[61] = {
  15,15,15,15,15,15,15, 14,14,14,14,14,14, 13,13,13,13,13,13,
  12,12,12,12,12,12, 11,11,11,11,11, 10,10,10,10,10,
  9,9,9,9, 8,8,8,8, 7,7,7,7, 6,6,6, 5,5,5, 4,4, 3,3, 2,2, 1, 0};
__device__ const unsigned char PT[16] = {1,1,2,2,2,3,3,4,4,4,5,5,6,6,6,7};
__device__ const unsigned char BS[16] = {60,59,57,55,53,50,47,43,39,35,30,25,19,13,7,0};

// ---------------------------------------------------------------------------
// Kernel 0: cast W -> bf16, rows [K:0-127][Q:128-255][V:256-383], Q pre-scaled.
// Also zeroes km.
// ---------------------------------------------------------------------------
__global__ __launch_bounds__(256) void castw_kernel(
    const float* __restrict__ Wk, const float* __restrict__ Wq,
    const float* __restrict__ Wv, __bf16* __restrict__ Wb,
    unsigned int* __restrict__ km) {
  if (blockIdx.x == 0 && threadIdx.x < 8) km[threadIdx.x] = 0u;
  int idx = blockIdx.x * 256 + threadIdx.x;
  int e   = idx * 4;
  int row = e >> 10;
  int col = e & 1023;
  const float* src;
  float sc = 1.0f;
  if (row < 128) {
    src = Wk + row * DIM_D + col;
  } else if (row < 256) {
    src = Wq + (row - 128) * DIM_D + col;
    sc  = 0.08838834764831845f;  // 1/sqrt(HS) folded into Wq
  } else {
    src = Wv + (row - 256) * DIM_D + col;
  }
  float4 v = *(const float4*)src;
  bf16x4_t o;
  o[0] = (__bf16)(v.x * sc); o[1] = (__bf16)(v.y * sc);
  o[2] = (__bf16)(v.z * sc); o[3] = (__bf16)(v.w * sc);
  *(bf16x4_t*)(Wb + e) = o;
}

// ---------------------------------------------------------------------------
// Kernel 1: projections v21 — cast phase FOLDED INTO the K-loop (T14 split).
// R11 closed the ledger: proj = SUM of comparable terms (serial cast ~13us,
// LDS ~10, MFMA ~5, L2 ~6) -> single-lever fixes all null; the win is
// OVERLAP. A-slab 64x128 bf16 (16 KB, dbuf), 8 phases x 4 K-steps. During
// phase p: 4 asm global_load_dwordx4 for slab p+1 issued at kt2==0 (HBM
// latency hides under 2 K-steps of MFMA), cvt+ds_write at kt2==2 behind
// WAIT_VM(6)+sched_barrier(0) (rule #18; asm loads so MY waits count, not
// compiler-conservative vmcnt(0)). Per-step counted waits: vmcnt(10) at
// kt2 in {1,2} while 4 x-loads in flight, vmcnt(6) else; tail 6/6/3/0.
// Phase handoff = lgkmcnt(0)+BAR (per-wave; B stages stay in flight).
// B = v19 quad-buffer, 1 BAR/K-step, no trailing drain (BAR-transitivity).
// LDS = 2x16384 (A) + 4x24576 (B) = 131072 -> 1 block/CU.
// Accumulation order unchanged -> bit-identical Q/K/V. Fused knorm kept.
// ---------------------------------------------------------------------------
__global__ __launch_bounds__(512, 1) void proj_kernel(
    const float* __restrict__ x, const __bf16* __restrict__ Wb,
    __bf16* __restrict__ Qb, __bf16* __restrict__ Kb, __bf16* __restrict__ Vt,
    unsigned int* __restrict__ km) {
  __shared__ __align__(16) char psmem[131072];
  // A: 2 x 16384 B at 0 (64 rows x 16 units x 16B, swizzled unit^(row&7))
  // B: 4 x 24576 B at 32768 (v19 layout)

  const int tid  = threadIdx.x;
  const int lane = tid & 63;
  const int wave = tid >> 6;     // 0..7
  const int h    = wave >> 2;    // m-half (0..1)
  const int g    = wave & 3;     // n-group (0..3)
  const int lr = lane & 15;
  const int lq = lane >> 4;
  const int m0 = blockIdx.x * 64;

  f32x4_t acc[2][6];
  #pragma unroll
  for (int mt = 0; mt < 2; ++mt)
    #pragma unroll
    for (int nt = 0; nt < 6; ++nt) acc[mt][nt] = (f32x4_t){0.f, 0.f, 0.f, 0.f};

  auto stageB = [&](int kt) {
    __bf16* Bs = (__bf16*)(psmem + 32768 + (kt & 3) * 24576);
    for (int c = wave; c < 24; c += 8) {     // 3 x 16B loads per wave
      const int row = c * 16 + (lane >> 2);
      const int u   = (lane & 3) ^ ((row >> 1) & 3);
      async_cp16(Wb + (size_t)row * DIM_D + kt * 32 + u * 8, Bs + c * 512);
    }
  };

  // x-cast: thread t handles row cr = t>>3, units cu and cu+8 of the slab.
  const int cr = tid >> 3;
  const int cu = tid & 7;
  f32x4_t xr0, xr1, xr2, xr3;
  auto castLoad = [&](int sp) {   // issue 4 asm loads for slab sp (cols sp*128..)
    const float* xs = x + (size_t)(m0 + cr) * DIM_D + sp * 128;
    const float* p0 = xs + cu * 8;
    const float* p1 = xs + cu * 8 + 4;
    const float* p2 = xs + (cu + 8) * 8;
    const float* p3 = xs + (cu + 8) * 8 + 4;
    asm volatile("global_load_dwordx4 %0, %1, off" : "=&v"(xr0) : "v"(p0));
    asm volatile("global_load_dwordx4 %0, %1, off" : "=&v"(xr1) : "v"(p1));
    asm volatile("global_load_dwordx4 %0, %1, off" : "=&v"(xr2) : "v"(p2));
    asm volatile("global_load_dwordx4 %0, %1, off" : "=&v"(xr3) : "v"(p3));
  };
  auto castStore = [&](int sp) {  // caller must have forced xr retirement
    __bf16* as = (__bf16*)(psmem + (sp & 1) * 16384) + cr * 128;
    const int sw = cr & 7;
    bf16x8_t a0, a1;
    a0[0] = (__bf16)xr0[0]; a0[1] = (__bf16)xr0[1];
    a0[2] = (__bf16)xr0[2]; a0[3] = (__bf16)xr0[3];
    a0[4] = (__bf16)xr1[0]; a0[5] = (__bf16)xr1[1];
    a0[6] = (__bf16)xr1[2]; a0[7] = (__bf16)xr1[3];
    a1[0] = (__bf16)xr2[0]; a1[1] = (__bf16)xr2[1];
    a1[2] = (__bf16)xr2[2]; a1[3] = (__bf16)xr2[3];
    a1[4] = (__bf16)xr3[0]; a1[5] = (__bf16)xr3[1];
    a1[6] = (__bf16)xr3[2]; a1[7] = (__bf16)xr3[3];
    *(bf16x8_t*)(as + ((cu ^ sw) * 8))       = a0;
    *(bf16x8_t*)(as + (((cu + 8) ^ sw) * 8)) = a1;
  };

  // Prologue: x-loads for slab 0 first (longest latency), then B stages.
  castLoad(0);
  stageB(0);
  stageB(1);
  WAIT_VM(6);      // 6 newer stage-loads outstanding allowed -> xr retired
  SCHEDBAR();
  castStore(0);
  WAIT_LGKM0;      // my ds_writes done (visibility after BAR); B stays in flight
  BAR(); FENCE();

  for (int p = 0; p < 8; ++p) {
    #pragma unroll
    for (int kt2 = 0; kt2 < 4; ++kt2) {
      const int kt = p * 4 + kt2;
      if (kt + 2 < 32) stageB(kt + 2);
      if (p < 7) {
        // x-loads (4) in flight between kt2==0 issue and kt2==2 consume
        if (kt2 == 0 || kt2 == 3) { WAIT_VM(6); } else { WAIT_VM(10); }
      } else {
        if (kt2 == 0 || kt2 == 1)      { WAIT_VM(6); }
        else if (kt2 == 2)             { WAIT_VM(3); }
        else                           { WAIT_VM(0); }
      }
      BAR(); FENCE();
      if (p < 7 && kt2 == 0) castLoad(p + 1);

      const __bf16* As = (const __bf16*)(psmem + (p & 1) * 16384);
      const __bf16* Bs = (const __bf16*)(psmem + 32768 + (kt & 3) * 24576);

      bf16x8_t af[2];
      #pragma unroll
      for (int mt = 0; mt < 2; ++mt) {
        const int ml = h * 32 + mt * 16 + lr;
        const int u  = kt2 * 4 + lq;          // unit 0..15 within slab
        af[mt] = *(const bf16x8_t*)(&As[ml * 128 + ((u ^ (ml & 7)) * 8)]);
      }
      bf16x8_t bfv[6];
      #pragma unroll
      for (int nt = 0; nt < 6; ++nt) {
        const int nl = g * 96 + nt * 16 + lr;
        bfv[nt] = *(const bf16x8_t*)(&Bs[nl * 32 + ((lq ^ ((nl >> 1) & 3)) * 8)]);
      }
      #pragma unroll
      for (int mt = 0; mt < 2; ++mt)
        #pragma unroll
        for (int nt = 0; nt < 6; ++nt)
          acc[mt][nt] = mfma_16x16x32(af[mt], bfv[nt], acc[mt][nt]);

      if (p < 7 && kt2 == 2) {
        SCHEDBAR();        // pin after MFMAs
        WAIT_VM(6);        // 6 newer stages allowed -> xr0..3 retired
        SCHEDBAR();        // rule #18: no hoist of cvt above the wait
        castStore(p + 1);
      }
      // no trailing drain/BAR: quad-B + BAR-transitivity (v19 argument)
    }
    WAIT_LGKM0;   // per-wave: my ds_reads + cast ds_writes complete
    BAR(); FENCE();
  }

  // ---- fused knorm: this block computes ALL 128 K-cols of rows m0..m0+63 ----
  __syncthreads();
  float* rowss = (float*)psmem;      // A region dead; reuse 64 floats
  if (tid < 64) rowss[tid] = 0.f;
  __syncthreads();
  if (g < 2) {                       // K cols live in g=0 (0..95), g=1 nt<2
    #pragma unroll
    for (int mt = 0; mt < 2; ++mt)
      #pragma unroll
      for (int r = 0; r < 4; ++r) {
        float s = 0.f;
        #pragma unroll
        for (int nt = 0; nt < 6; ++nt)
          if (g == 0 || nt < 2) s += acc[mt][nt][r] * acc[mt][nt][r];
        s += __shfl_xor(s, 1); s += __shfl_xor(s, 2);
        s += __shfl_xor(s, 4); s += __shfl_xor(s, 8);
        if (lr == 0) atomicAdd(&rowss[h * 32 + mt * 16 + lq * 4 + r], s);
      }
  }
  __syncthreads();
  if (tid < 64) {
    float v = rowss[tid];
    #pragma unroll
    for (int off = 1; off < 64; off <<= 1) v = fmaxf(v, __shfl_xor(v, off));
    if (tid == 0) atomicMax(km + (m0 >> 11), __float_as_uint(v));
  }

  #pragma unroll
  for (int mt = 0; mt < 2; ++mt) {
    const int t0 = m0 + h * 32 + mt * 16 + lq * 4;
    #pragma unroll
    for (int nt = 0; nt < 6; ++nt) {
      const int nn = g * 96 + nt * 16 + lr;
      if (nn < 256) {
        __bf16* dst = (nn < 128) ? (Kb + nn) : (Qb + (nn - 128));
        #pragma unroll
        for (int r = 0; r < 4; ++r)
          dst[(size_t)(t0 + r) * HS_N] = (__bf16)acc[mt][nt][r];
      } else {
        const int bb = t0 >> 11;
        const int tl = t0 & 2047;
        bf16x4_t o;
        #pragma unroll
        for (int r = 0; r < 4; ++r) o[r] = (__bf16)acc[mt][nt][r];
        *(bf16x4_t*)(Vt + (size_t)bb * (HS_N * SEQ_T) + (size_t)(nn - 256) * SEQ_T + tl) = o;
      }
    }
  }
}

// ---------------------------------------------------------------------------
// Kernel 2: flash attention v8 — v7 core, rebalanced partition: (b,jg) split
// into PT[jg] = ceil(2(jg+1)/5) parts -> makespan 8->5 chunks. Grid 488
// (61 slots x 8 batches), all co-resident. Chunk range for part p of P:
// [p*ch/P, (p+1)*ch/P). Everything else identical to R3's verified v7.
// ---------------------------------------------------------------------------
__global__ __launch_bounds__(256, 2) void attn_kernel(
    const __bf16* __restrict__ Qb, const __bf16* __restrict__ Kb,
    const __bf16* __restrict__ Vt, const unsigned int* __restrict__ km,
    __bf16* __restrict__ Opart, float* __restrict__ lpart) {
  __shared__ __align__(16) char smem[81920];
  __bf16* KsBase = (__bf16*)smem;                    // 2 x 16 KB
  __bf16* VsBase = (__bf16*)(smem + 32768);          // 2 x 16 KB
  float*  Ofl    = (float*)smem;                     // 128x132 fp32, post-loop

  const int lane = threadIdx.x & 63;
  const int wave = threadIdx.x >> 6;       // 0..3
  const int lr = lane & 15;
  const int lq = lane >> 4;
  const int bid  = blockIdx.x;
  const int b    = bid & 7;                // batch -> XCD pinned
  const int slot = bid >> 3;               // 0..60, heavy-first
  const int jg   = SJG[slot];
  const int pp   = slot - BS[jg];          // part index within (b,jg)
  const int P    = PT[jg];
  const int Q0   = jg * 128;
  const int qa   = Q0 + wave * 32;         // this wave's 32 rows (2 tiles)
  const int ch   = 2 * (jg + 1);           // total 64-key chunks for this jg
  const int c0   = (pp * ch) / P;
  const int c1   = ((pp + 1) * ch) / P;

  const __bf16* Qbb = Qb + (size_t)b * (SEQ_T * HS_N);
  const __bf16* Kbb = Kb + (size_t)b * (SEQ_T * HS_N);
  const __bf16* Vbb = Vt + (size_t)b * (HS_N * SEQ_T);
  __bf16* pbA = (__bf16*)(smem + 65536 + wave * 4096);         // 16x64 bf16
  __bf16* pbB = (__bf16*)(smem + 65536 + wave * 4096 + 2048);  // 16x64 bf16

  bf16x8_t qf[2][4];
  #pragma unroll
  for (int t = 0; t < 2; ++t)
    #pragma unroll
    for (int ks = 0; ks < 4; ++ks)
      qf[t][ks] = *(const bf16x8_t*)(Qbb + (size_t)(qa + t * 16 + lr) * HS_N
                                     + ks * 32 + lq * 8);

  const float km2 = __uint_as_float(km[b]);
  float mrow[2][4];
  #pragma unroll
  for (int t = 0; t < 2; ++t) {
    float qn2 = 0.f;
    #pragma unroll
    for (int ks = 0; ks < 4; ++ks)
      #pragma unroll
      for (int j = 0; j < 8; ++j) { float f = (float)qf[t][ks][j]; qn2 += f * f; }
    qn2 += __shfl_xor(qn2, 16);
    qn2 += __shfl_xor(qn2, 32);
    #pragma unroll
    for (int r2 = 0; r2 < 4; ++r2)
      mrow[t][r2] = sqrtf(__shfl(qn2, lq * 4 + r2) * km2);
  }

  f32x4_t Oa[2][8];
  #pragma unroll
  for (int t = 0; t < 2; ++t)
    #pragma unroll
    for (int o = 0; o < 8; ++o) Oa[t][o] = (f32x4_t){0.f, 0.f, 0.f, 0.f};
  float lsum[2][4] = {{0.f,0.f,0.f,0.f},{0.f,0.f,0.f,0.f}};

  auto stage = [&](int bufi, int c) {
    const int kk = c * 64;
    __bf16* Ks = KsBase + bufi * 8192;
    for (int idx = wave; idx < 32; idx += 4) {   // 8 x 16B loads per wave
      if (idx < 16) {          // K: 4 rows x 256B per call
        const int row = idx * 4 + (lane >> 4);
        const int u   = (lane & 15) ^ (row & 15);
        async_cp16(Kbb + (size_t)(kk + row) * HS_N + u * 8, Ks + idx * 512);
      } else {                 // V: 8 rows x 128B per call (rows = HS dims)
        const int i2  = idx - 16;
        const int row = i2 * 8 + (lane >> 3);
        const int u   = (lane & 7) ^ (row & 7);
        async_cp16(Vbb + (size_t)row * SEQ_T + kk + u * 8, VsBase + bufi * 8192 + i2 * 512);
      }
    }
  };

  if (c0 < c1) stage(0, c0);
  __syncthreads();   // prologue: full drain once

  for (int c = c0; c < c1; ++c) {
    const int cur = (c - c0) & 1;
    if (c + 1 < c1) {
      stage(cur ^ 1, c + 1);   // 8 loads/wave stay in flight across BAR
      WAIT_VM(8);              // only chunk c's batch must be complete
    } else {
      WAIT_VM(0);
    }
    BAR();                     // all waves: buf[cur] fully written
    FENCE();

    const int kk = c * 64;
    const __bf16* Ks = KsBase + cur * 8192;
    const __bf16* Vs = VsBase + cur * 8192;

    f32x4_t s0[4], s1[4];
    #pragma unroll
    for (int nt = 0; nt < 4; ++nt) {
      s0[nt] = (f32x4_t){0.f, 0.f, 0.f, 0.f};
      s1[nt] = (f32x4_t){0.f, 0.f, 0.f, 0.f};
    }
    #pragma unroll
    for (int ks = 0; ks < 4; ++ks)
      #pragma unroll
      for (int nt = 0; nt < 4; ++nt) {
        bf16x8_t kf = *(const bf16x8_t*)(
            &Ks[(nt * 16 + lr) * 128 + (((ks * 4 + lq) ^ lr) * 8)]);
        s0[nt] = mfma_16x16x32(qf[0][ks], kf, s0[nt]);
        s1[nt] = mfma_16x16x32(qf[1][ks], kf, s1[nt]);
      }
    const int q0a = qa, q0b = qa + 16;
    if (kk + 63 > q0a) {
      #pragma unroll
      for (int nt = 0; nt < 4; ++nt) {
        const int col = kk + nt * 16 + lr;
        #pragma unroll
        for (int r2 = 0; r2 < 4; ++r2)
          if (col > q0a + lq * 4 + r2) s0[nt][r2] = -INFINITY;
      }
    }
    if (kk + 63 > q0b) {
      #pragma unroll
      for (int nt = 0; nt < 4; ++nt) {
        const int col = kk + nt * 16 + lr;
        #pragma unroll
        for (int r2 = 0; r2 < 4; ++r2)
          if (col > q0b + lq * 4 + r2) s1[nt][r2] = -INFINITY;
      }
    }

    #pragma unroll
    for (int r2 = 0; r2 < 4; ++r2) {
      float a0 = __expf(s0[0][r2] - mrow[0][r2]);
      float a1 = __expf(s0[1][r2] - mrow[0][r2]);
      float a2 = __expf(s0[2][r2] - mrow[0][r2]);
      float a3 = __expf(s0[3][r2] - mrow[0][r2]);
      s0[0][r2] = a0; s0[1][r2] = a1; s0[2][r2] = a2; s0[3][r2] = a3;
      lsum[0][r2] += (a0 + a1) + (a2 + a3);
      float b0 = __expf(s1[0][r2] - mrow[1][r2]);
      float b1 = __expf(s1[1][r2] - mrow[1][r2]);
      float b2 = __expf(s1[2][r2] - mrow[1][r2]);
      float b3 = __expf(s1[3][r2] - mrow[1][r2]);
      s1[0][r2] = b0; s1[1][r2] = b1; s1[2][r2] = b2; s1[3][r2] = b3;
      lsum[1][r2] += (b0 + b1) + (b2 + b3);
    }

    #pragma unroll
    for (int nt = 0; nt < 4; ++nt)
      #pragma unroll
      for (int r2 = 0; r2 < 4; ++r2) {
        const int prow = lq * 4 + r2;
        const int pcol = (nt * 16 + lr) ^ ((prow & 7) << 3);
        pbA[prow * 64 + pcol] = (__bf16)s0[nt][r2];
        pbB[prow * 64 + pcol] = (__bf16)s1[nt][r2];
      }

    #pragma unroll
    for (int k2 = 0; k2 < 2; ++k2) {
      const int au = ((k2 * 4 + lq) ^ (lr & 7)) << 3;
      bf16x8_t afrA = *(const bf16x8_t*)(pbA + lr * 64 + au);
      bf16x8_t afrB = *(const bf16x8_t*)(pbB + lr * 64 + au);
      #pragma unroll
      for (int o = 0; o < 8; ++o) {
        bf16x8_t vfr = *(const bf16x8_t*)(
            &Vs[(o * 16 + lr) * 64 + (((k2 * 4 + lq) ^ (lr & 7)) * 8)]);
        Oa[0][o] = mfma_16x16x32(afrA, vfr, Oa[0][o]);
        Oa[1][o] = mfma_16x16x32(afrB, vfr, Oa[1][o]);
      }
    }
    WAIT_LGKM0;                // my LDS reads (K/V/P) complete
    BAR();                     // release buf[cur] for overwrite next iter
    FENCE();
  }

  #pragma unroll
  for (int t = 0; t < 2; ++t)
    #pragma unroll
    for (int r2 = 0; r2 < 4; ++r2) {
      float v = lsum[t][r2];
      v += __shfl_xor(v, 1);
      v += __shfl_xor(v, 2);
      v += __shfl_xor(v, 4);
      v += __shfl_xor(v, 8);
      if (lr == 0)
        lpart[bid * 128 + wave * 32 + t * 16 + lq * 4 + r2] = v;
    }

  #pragma unroll
  for (int t = 0; t < 2; ++t)
    #pragma unroll
    for (int o = 0; o < 8; ++o)
      #pragma unroll
      for (int r2 = 0; r2 < 4; ++r2)
        Ofl[(wave * 32 + t * 16 + lq * 4 + r2) * 132 + o * 16 + lr] = Oa[t][o][r2];
  __syncthreads();

  {
    const int row = threadIdx.x >> 1;
    const int cb  = (threadIdx.x & 1) * 64;
    __bf16* dst = Opart + ((size_t)bid * 128 + row) * 128 + cb;
    #pragma unroll
    for (int g2 = 0; g2 < 16; ++g2) {
      float4 f = *(const float4*)(&Ofl[row * 132 + cb + g2 * 4]);
      bf16x4_t o;
      o[0] = (__bf16)f.x; o[1] = (__bf16)f.y; o[2] = (__bf16)f.z; o[3] = (__bf16)f.w;
      *(bf16x4_t*)(dst + g2 * 4) = o;
    }
  }
}

// ---------------------------------------------------------------------------
// Kernel 3: merge the PT[jg] key-parts: out = (sum O_p) / (sum l_p)
// ---------------------------------------------------------------------------
__global__ __launch_bounds__(256) void merge_kernel(
    const __bf16* __restrict__ Opart, const float* __restrict__ lpart,
    float* __restrict__ out) {
  const int idx = blockIdx.x * 256 + threadIdx.x;   // 524288 threads
  const int row = idx >> 5;                         // global row 0..16383
  const int c4  = (idx & 31) * 4;
  const int b   = row >> 11;
  const int tl  = row & 2047;
  const int jg  = tl >> 7;
  const int lrow = tl & 127;
  const int P    = PT[jg];
  const int base = BS[jg];
  float a0 = 0.f, a1 = 0.f, a2 = 0.f, a3 = 0.f, l = 0.f;
  for (int p = 0; p < P; ++p) {
    const int s = b + 8 * (base + p);
    bf16x4_t a = *(const bf16x4_t*)(Opart + ((size_t)s * 128 + lrow) * 128 + c4);
    a0 += (float)a[0]; a1 += (float)a[1]; a2 += (float)a[2]; a3 += (float)a[3];
    l += lpart[s * 128 + lrow];
  }
  const float inv = 1.0f / l;
  float4 o;
  o.x = a0 * inv; o.y = a1 * inv; o.z = a2 * inv; o.w = a3 * inv;
  *(float4*)(out + (size_t)row * HS_N + c4) = o;
}

// ---------------------------------------------------------------------------
extern "C" void kernel_launch(void* const* d_in, const int* in_sizes, int n_in,
                              void* d_out, int out_size, void* d_ws, size_t ws_size,
                              hipStream_t stream) {
  const float* x  = (const float*)d_in[0];
  const float* Wk = (const float*)d_in[1];
  const float* Wq = (const float*)d_in[2];
  const float* Wv = (const float*)d_in[3];
  float* out = (float*)d_out;

  char* ws = (char*)d_ws;
  __bf16* Wb = (__bf16*)ws;                          //   786432 B
  __bf16* Qb = (__bf16*)(ws + 786432);               //  4194304 B
  __bf16* Kb = (__bf16*)(ws + 786432 + 4194304);     //  4194304 B
  __bf16* Vt = (__bf16*)(ws + 786432 + 8388608);     //  4194304 B
  unsigned int* km = (unsigned int*)(ws + 13369344); //       32 B
  __bf16* Opart = (__bf16*)(ws + 13369600);          // <=16 MB (488x128x128)
  float*  lpart = (float*)(ws + 30146816);           //   <=250 KB

  castw_kernel<<<384, 256, 0, stream>>>(Wk, Wq, Wv, Wb, km);
  proj_kernel<<<256, 512, 0, stream>>>(x, Wb, Qb, Kb, Vt, km);
  attn_kernel<<<488, 256, 0, stream>>>(Qb, Kb, Vt, km, Opart, lpart);
  merge_kernel<<<2048, 256, 0, stream>>>(Opart, lpart, out);
}